// Round 2
// baseline (977.464 us; speedup 1.0000x reference)
//
#include <hip/hip_runtime.h>

// ---------------- problem constants ----------------
#define N_PTS 98304
#define SY 468
#define SX 468
#define WIN 12
#define MWY 40
#define PER 1600          // mwx*mwy = 40*40
#define NWIN 3200         // B*PER
#define NSLOT (NWIN*144)
#define NDENSE (2*SY*SX)

using bf16x8 = __attribute__((ext_vector_type(8))) short;
using f32x4  = __attribute__((ext_vector_type(4))) float;

__device__ __forceinline__ unsigned short f2bf(float f){
  unsigned u = __float_as_uint(f);
  u += 0x7fffu + ((u>>16)&1u);          // RNE
  return (unsigned short)(u>>16);
}
__device__ __forceinline__ float2 bfp2(unsigned u){
  float2 r; r.x = __uint_as_float(u<<16); r.y = __uint_as_float(u & 0xffff0000u); return r;
}
__device__ __forceinline__ unsigned fpack2(float a, float b){
  return (unsigned)f2bf(a) | ((unsigned)f2bf(b)<<16);
}

// ---------------- workspace layout (bytes) ----------------
constexpr size_t OFF_SORTED = 0;
constexpr size_t OFF_SLOT   = OFF_SORTED + (size_t)N_PTS*4;
constexpr size_t OFF_CNT    = OFF_SLOT + (size_t)NSLOT*4;
constexpr size_t OFF_OFFS   = OFF_CNT + (size_t)NWIN*4;
constexpr size_t OFF_STATS  = OFF_OFFS + (size_t)NWIN*4;     // 3 x (sum[128],sumsq[128])
constexpr size_t OFF_SB     = OFF_STATS + 3*256*4;           // 3 x (scale[128],bias[128])
constexpr size_t OFF_BQKV   = OFF_SB + 3*256*4;              // float[384] (padded)
constexpr size_t OFF_B1     = OFF_BQKV + 512*4;              // float[256]
constexpr size_t OFF_WQKV   = OFF_B1 + 256*4;                // bf16 128x384 packed
constexpr size_t OFF_WOUT   = OFF_WQKV + (size_t)128*384*2;
constexpr size_t OFF_W1     = OFF_WOUT + (size_t)128*128*2;
constexpr size_t OFF_W2     = OFF_W1 + (size_t)128*256*2;
constexpr size_t OFF_WCONV  = OFF_W2 + (size_t)256*128*2;    // bf16 [35][32][32] (tap,co,ci)
constexpr size_t OFF_DENSE  = OFF_WCONV + (size_t)35*1024*2;
constexpr size_t OFF_QKV    = (OFF_DENSE + (size_t)NDENSE*4 + 255) & ~(size_t)255; // qkv bf16 Nx384
constexpr size_t OFF_SRC    = OFF_QKV;                        // (reuse) src fp32 Nx128
constexpr size_t OFF_SRCB   = OFF_QKV + (size_t)N_PTS*128*4;  // (reuse) src bf16 Nx128
constexpr size_t OFF_ATT    = OFF_QKV + (size_t)N_PTS*384*2;  // attout bf16 Nx128
constexpr size_t OFF_SRCNB  = OFF_ATT;                        // (reuse) srcn bf16
constexpr size_t OFF_F2     = OFF_ATT + (size_t)N_PTS*128*2;  // feats2 fp32 Nx128
constexpr size_t OFF_H      = OFF_F2;                         // (reuse) H bf16 Nx256 (same bytes)
constexpr size_t OFF_SRCNF  = OFF_F2 + (size_t)N_PTS*128*4;   // srcn fp32 Nx128
// total ~206 MB

// ---------------- small utility kernels ----------------
__global__ void fill_i32(int* p, int v, int n){
  int i = blockIdx.x*256 + threadIdx.x;
  if (i < n) p[i] = v;
}

__global__ void keys_kernel(const int* __restrict__ coords, int* __restrict__ slot){
  int i = blockIdx.x*256 + threadIdx.x;
  if (i >= N_PTS) return;
  int cb = coords[3*i], cy = coords[3*i+1], cx = coords[3*i+2];
  int w = cb*PER + (cx/WIN)*MWY + (cy/WIN);
  int sub = (cx%WIN)*WIN + (cy%WIN);
  slot[w*144 + sub] = i;         // keys unique -> no collision
}

__global__ void wincount_kernel(const int* __restrict__ slot, int* __restrict__ cnt){
  int w = blockIdx.x*256 + threadIdx.x;
  if (w >= NWIN) return;
  int c = 0;
  for (int s = 0; s < 144; ++s) c += (slot[w*144+s] >= 0);
  cnt[w] = c;
}

__global__ void scan_kernel(const int* __restrict__ cnt, int* __restrict__ offs){
  __shared__ int tsum[256];
  int tid = threadIdx.x;
  int loc[13]; int s = 0;
  #pragma unroll
  for (int j = 0; j < 13; ++j){
    int idx = tid*13 + j;
    int v = (idx < NWIN) ? cnt[idx] : 0;
    loc[j] = s; s += v;
  }
  tsum[tid] = s;
  __syncthreads();
  for (int off = 1; off < 256; off <<= 1){
    int v = (tid >= off) ? tsum[tid-off] : 0;
    __syncthreads();
    tsum[tid] += v;
    __syncthreads();
  }
  int pre = (tid > 0) ? tsum[tid-1] : 0;
  #pragma unroll
  for (int j = 0; j < 13; ++j){
    int idx = tid*13 + j;
    if (idx < NWIN) offs[idx] = pre + loc[j];
  }
}

__global__ void scatter_kernel(const int* __restrict__ slot, const int* __restrict__ offs,
                               int* __restrict__ sorted){
  int w = blockIdx.x*256 + threadIdx.x;
  if (w >= NWIN) return;
  int o = offs[w];
  for (int s = 0; s < 144; ++s){
    int v = slot[w*144+s];
    if (v >= 0) sorted[o++] = v;
  }
}

__global__ void dense_kernel(const int* __restrict__ coords, int* __restrict__ dense){
  int i = blockIdx.x*256 + threadIdx.x;
  if (i >= N_PTS) return;
  dense[(coords[3*i]*SY + coords[3*i+1])*SX + coords[3*i+2]] = i;
}

__global__ __launch_bounds__(256) void bnstats_kernel(const float* __restrict__ x, float* __restrict__ stats){
  __shared__ float sh[256], shq[256];
  int tid = threadIdx.x;
  int c = tid & 127;
  float s = 0.f, q = 0.f;
  for (int r = blockIdx.x*2 + (tid>>7); r < N_PTS; r += gridDim.x*2){
    float v = x[(size_t)r*128 + c];
    s += v; q += v*v;
  }
  sh[tid] = s; shq[tid] = q;
  __syncthreads();
  if (tid < 128){
    atomicAdd(&stats[tid],     sh[tid] + sh[tid+128]);
    atomicAdd(&stats[128+tid], shq[tid] + shq[tid+128]);
  }
}

__global__ void bnfinish_kernel(const float* __restrict__ stats, const float* __restrict__ g,
                                const float* __restrict__ b, float* __restrict__ sb){
  int c = threadIdx.x;
  if (c >= 128) return;
  float mean = stats[c] * (1.0f/N_PTS);
  float var  = stats[128+c] * (1.0f/N_PTS) - mean*mean;
  float s = g[c] * rsqrtf(var + 1e-3f);
  sb[c] = s;
  sb[128+c] = b[c] - mean*s;
}

// pack W (row-major KxN, fp32) into per-lane MFMA B-fragment order, bf16.
// index = (((np*KT + kt)*8 + jt)*64 + lane)*8 + e  ->  W[kt*32 + (lane>>4)*8 + e][np*128 + jt*16 + (lane&15)]
__global__ void packw_kernel(const float* __restrict__ W, const float* __restrict__ scale,
                             short* __restrict__ out, int K, int Nn){
  int t = blockIdx.x*256 + threadIdx.x;
  if (t >= K*Nn) return;
  int e = t & 7, l = (t>>3) & 63, jt = (t>>9) & 7;
  int rest = t >> 12;
  int KT = K >> 5;
  int kt = rest % KT, np = rest / KT;
  int k = kt*32 + ((l>>4)<<3) + e;
  int col = np*128 + jt*16 + (l&15);
  float v = W[(size_t)k*Nn + col];
  if (scale) v *= scale[k];
  out[t] = (short)f2bf(v);
}

__global__ void packbias_kernel(const float* __restrict__ W, const float* __restrict__ bvec,
                                const float* __restrict__ base, float* __restrict__ out, int K, int Nn){
  int o = blockIdx.x*256 + threadIdx.x;
  if (o >= Nn) return;
  float s = base ? base[o] : 0.f;
  for (int k = 0; k < K; ++k) s += bvec[k] * W[(size_t)k*Nn + o];
  out[o] = s;
}

__global__ void packconv_kernel(const float* __restrict__ wk, const float* __restrict__ wh,
                                const float* __restrict__ ww, short* __restrict__ out){
  int t = blockIdx.x*256 + threadIdx.x;
  if (t >= 35*1024) return;
  int tap = t >> 10, r = t & 1023, co = r >> 5, ci = r & 31;
  float v;
  if (tap < 9)       v = wk[((size_t)(tap*32) + ci)*32 + co];
  else if (tap < 22) v = wh[((size_t)((tap-9)*32) + ci)*32 + co];
  else               v = ww[((size_t)((tap-22)*32) + ci)*32 + co];
  out[((size_t)tap*32 + co)*32 + ci] = (short)f2bf(v);   // [tap][cout][cin]
}

__global__ __launch_bounds__(256) void srcn_kernel(const float* __restrict__ f2, const float* __restrict__ sb,
                            float* __restrict__ sf, short* __restrict__ sbuf){
  size_t i = (size_t)blockIdx.x*256 + threadIdx.x;
  if (i >= (size_t)N_PTS*32) return;
  int c4 = ((int)(i & 31)) * 4;
  float4 v = ((const float4*)f2)[i];
  float4 o;
  o.x = v.x*sb[c4+0] + sb[128+c4+0];
  o.y = v.y*sb[c4+1] + sb[128+c4+1];
  o.z = v.z*sb[c4+2] + sb[128+c4+2];
  o.w = v.w*sb[c4+3] + sb[128+c4+3];
  ((float4*)sf)[i] = o;
  uint2 h; h.x = fpack2(o.x, o.y); h.y = fpack2(o.z, o.w);
  ((uint2*)sbuf)[i] = h;
}

// ---------------- generic 128-row-tile MFMA GEMM ----------------
// AMODE 0: A rows gathered from fp32 via sorted[]   AMODE 1: A rows direct bf16 (stride K)
// EPI 0: store bf16 (stride dstStride, +bias)
// EPI 1: feats2[sorted[row]] = addf[sorted[row]] + acc + bias   (fc_out + residual scatter)
// EPI 2: relu then store bf16
// EPI 3: outf[row] = addf[row] + acc + bias (fp32, stride 128)
template<int K, int AMODE, int EPI>
__global__ __launch_bounds__(256) void gemm_kernel(
    const float* __restrict__ Afp, const short* __restrict__ Abf,
    const int* __restrict__ sorted, const short* __restrict__ Wp,
    const float* __restrict__ bias, const float* __restrict__ addf,
    float* __restrict__ outf, short* __restrict__ outb, int dstStride)
{
  extern __shared__ char smem[];   // A tile: 128 x K bf16, XOR-swizzled
  const int m0 = blockIdx.x * 128;
  const int np = blockIdx.y;
  const int tid = threadIdx.x;
  if (AMODE == 0){
    const int CHK = K/4;
    for (int c = tid; c < 128*CHK; c += 256){
      int r = c / CHK, q = c % CHK;
      const float* arow = Afp + (size_t)sorted[m0+r]*K;
      float4 v = ((const float4*)arow)[q];
      int off = r*(K*2) + q*8; off ^= ((r&7)<<4);
      *reinterpret_cast<uint2*>(smem+off) = make_uint2(fpack2(v.x,v.y), fpack2(v.z,v.w));
    }
  } else {
    const int CHK = K/8;
    for (int c = tid; c < 128*CHK; c += 256){
      int r = c / CHK, q = c % CHK;
      uint4 v = ((const uint4*)(Abf + (size_t)(m0+r)*K))[q];
      int off = r*(K*2) + q*16; off ^= ((r&7)<<4);
      *reinterpret_cast<uint4*>(smem+off) = v;
    }
  }
  __syncthreads();
  const int w = tid >> 6, l = tid & 63, lg = l >> 4, l16 = l & 15;
  f32x4 zacc; zacc[0]=0.f; zacc[1]=0.f; zacc[2]=0.f; zacc[3]=0.f;
  f32x4 acc[2][8];
  #pragma unroll
  for (int mt=0; mt<2; ++mt)
    #pragma unroll
    for (int jt=0; jt<8; ++jt) acc[mt][jt] = zacc;
  const int KT = K/32;
  #pragma unroll
  for (int kt = 0; kt < KT; ++kt){
    const short* wk = Wp + ((size_t)(np*KT + kt))*4096;
    bf16x8 bfr[8];
    #pragma unroll
    for (int jt=0; jt<8; ++jt)
      bfr[jt] = *reinterpret_cast<const bf16x8*>(wk + jt*512 + l*8);
    #pragma unroll
    for (int mt=0; mt<2; ++mt){
      int row = w*32 + mt*16 + l16;
      int off = row*(K*2) + kt*64 + lg*16; off ^= ((row&7)<<4);
      bf16x8 af = *reinterpret_cast<const bf16x8*>(smem + off);
      #pragma unroll
      for (int jt=0; jt<8; ++jt)
        acc[mt][jt] = __builtin_amdgcn_mfma_f32_16x16x32_bf16(af, bfr[jt], acc[mt][jt], 0, 0, 0);
    }
  }
  #pragma unroll
  for (int mt=0; mt<2; ++mt){
    #pragma unroll
    for (int jt=0; jt<8; ++jt){
      int col = np*128 + jt*16 + l16;
      float bv = bias ? bias[col] : 0.f;
      #pragma unroll
      for (int e=0; e<4; ++e){
        int row = m0 + w*32 + mt*16 + lg*4 + e;
        float v = acc[mt][jt][e] + bv;
        if (EPI == 0){
          outb[(size_t)row*dstStride + col] = (short)f2bf(v);
        } else if (EPI == 1){
          int gi = sorted[row];
          outf[(size_t)gi*128 + col] = addf[(size_t)gi*128 + col] + v;
        } else if (EPI == 2){
          outb[(size_t)row*dstStride + col] = (short)f2bf(fmaxf(v, 0.f));
        } else {
          outf[(size_t)row*128 + col] = addf[(size_t)row*128 + col] + v;
        }
      }
    }
  }
}

// ---------------- fused grouped attention ----------------
// one block per group of 128 sorted tokens; 4 waves, wave w owns query rows [w*32,w*32+32)
__global__ __launch_bounds__(256) void attn_kernel(const short* __restrict__ qkv, short* __restrict__ attout){
  extern __shared__ char smem[];
  char* Qs = smem;            // 128x128 bf16 swizzled
  char* Ks = smem + 32768;
  char* VT = smem + 65536;    // VT[ch][key]
  char* Ps = smem + 98304;    // P, per-wave private rows
  const int g = blockIdx.x;
  const int tid = threadIdx.x;
  for (int c = tid; c < 128*48; c += 256){
    int r = c / 48, q = c % 48;
    uint4 v = ((const uint4*)(qkv + ((size_t)(g*128 + r))*384))[q];
    int ch0 = q*8;
    if (ch0 < 128){
      int off = r*256 + ch0*2; off ^= ((r&7)<<4);
      *reinterpret_cast<uint4*>(Qs + off) = v;
    } else if (ch0 < 256){
      int off = r*256 + (ch0-128)*2; off ^= ((r&7)<<4);
      *reinterpret_cast<uint4*>(Ks + off) = v;
    } else {
      const unsigned short* hv = reinterpret_cast<const unsigned short*>(&v);
      #pragma unroll
      for (int j=0; j<8; ++j){
        int cc = ch0 - 256 + j;
        int off = cc*256 + r*2; off ^= ((cc&7)<<4);
        *reinterpret_cast<unsigned short*>(VT + off) = hv[j];
      }
    }
  }
  __syncthreads();
  const int w = tid>>6, l = tid&63, lg = l>>4, l16 = l&15;
  const int r0 = w*32;
  const float sc = 0.08838834764831845f;  // 1/sqrt(128)
  bf16x8 zero8;
  #pragma unroll
  for (int j=0;j<8;++j) zero8[j]=0;
  f32x4 zacc; zacc[0]=0.f; zacc[1]=0.f; zacc[2]=0.f; zacc[3]=0.f;
  for (int h=0; h<8; ++h){
    f32x4 s[2][8];
    #pragma unroll
    for (int mt=0;mt<2;++mt)
      #pragma unroll
      for (int jt=0;jt<8;++jt) s[mt][jt] = zacc;
    bf16x8 qa[2];
    #pragma unroll
    for (int mt=0; mt<2; ++mt){
      if (lg < 2){                      // K=16 zero-padded to 32
        int row = r0 + mt*16 + l16;
        int off = row*256 + h*32 + lg*16; off ^= ((row&7)<<4);
        qa[mt] = *reinterpret_cast<const bf16x8*>(Qs + off);
      } else qa[mt] = zero8;
    }
    #pragma unroll
    for (int jt=0; jt<8; ++jt){
      bf16x8 kb;
      if (lg < 2){
        int key = jt*16 + l16;
        int off = key*256 + h*32 + lg*16; off ^= ((key&7)<<4);
        kb = *reinterpret_cast<const bf16x8*>(Ks + off);
      } else kb = zero8;
      #pragma unroll
      for (int mt=0; mt<2; ++mt)
        s[mt][jt] = __builtin_amdgcn_mfma_f32_16x16x32_bf16(qa[mt], kb, s[mt][jt], 0,0,0);
    }
    // in-register softmax (row i lives in one 16-lane group, reg e)
    #pragma unroll
    for (int mt=0; mt<2; ++mt){
      #pragma unroll
      for (int e=0; e<4; ++e){
        float m = -1e30f;
        #pragma unroll
        for (int jt=0; jt<8; ++jt){
          float t = s[mt][jt][e] * sc;
          s[mt][jt][e] = t;
          m = fmaxf(m, t);
        }
        #pragma unroll
        for (int off=1; off<16; off<<=1) m = fmaxf(m, __shfl_xor(m, off));
        float d = 0.f;
        #pragma unroll
        for (int jt=0; jt<8; ++jt){
          float p = __expf(s[mt][jt][e] - m);
          s[mt][jt][e] = p; d += p;
        }
        #pragma unroll
        for (int off=1; off<16; off<<=1) d += __shfl_xor(d, off);
        float inv = 1.0f / d;
        #pragma unroll
        for (int jt=0; jt<8; ++jt) s[mt][jt][e] *= inv;
      }
      #pragma unroll
      for (int jt=0; jt<8; ++jt){
        #pragma unroll
        for (int e=0; e<4; ++e){
          int row = r0 + mt*16 + lg*4 + e;
          int off = row*256 + (jt*16 + l16)*2; off ^= ((row&7)<<4);
          *reinterpret_cast<unsigned short*>(Ps + off) = f2bf(s[mt][jt][e]);
        }
      }
    }
    __syncthreads();
    #pragma unroll
    for (int mt=0; mt<2; ++mt){
      f32x4 o = zacc;
      #pragma unroll
      for (int kt=0; kt<4; ++kt){
        int row = r0 + mt*16 + l16;
        int offp = row*256 + kt*64 + lg*16; offp ^= ((row&7)<<4);
        bf16x8 pa = *reinterpret_cast<const bf16x8*>(Ps + offp);
        int cc = h*16 + l16;
        int offv = cc*256 + kt*64 + lg*16; offv ^= ((cc&7)<<4);
        bf16x8 vb = *reinterpret_cast<const bf16x8*>(VT + offv);
        o = __builtin_amdgcn_mfma_f32_16x16x32_bf16(pa, vb, o, 0,0,0);
      }
      #pragma unroll
      for (int e=0; e<4; ++e){
        int row = g*128 + r0 + mt*16 + lg*4 + e;
        attout[(size_t)row*128 + h*16 + l16] = (short)f2bf(o[e]);
      }
    }
    __syncthreads();
  }
}

// ---------------- submanifold convs (VALU, round 1) ----------------
// blockIdx.y = conv group g (0: 3x3 on ch0:32, 1: 1x13 on ch32:64, 2: 13x1 on ch64:96)
// block = 256 threads = 8 points x 32 cout, 4 iterations -> 32 points/block
__global__ __launch_bounds__(256) void conv_kernel(
    const short* __restrict__ wconv, const short* __restrict__ srcnb,
    const float* __restrict__ srcnf, const int* __restrict__ dense,
    const int* __restrict__ coords, float* __restrict__ src)
{
  extern __shared__ char smem[];
  short* wl  = (short*)smem;                 // [tc][32][36]  (pad 36 kills bank conflicts)
  short* nbf = wl + 13*32*36;                // [8][13][32]
  int*   nid = (int*)(nbf + 8*13*32);        // [8][13]
  const int g = blockIdx.y;
  const int tc   = (g==0) ? 9 : 13;
  const int tap0 = (g==0) ? 0 : ((g==1) ? 9 : 22);
  const int tid = threadIdx.x;
  for (int i = tid; i < tc*1024; i += 256){
    int tap = i >> 10, r = i & 1023, co = r >> 5, ci = r & 31;
    wl[(tap*32+co)*36 + ci] = wconv[((size_t)(tap0+tap)*32 + co)*32 + ci];
  }
  __syncthreads();
  const int p0 = blockIdx.x * 32;
  for (int it = 0; it < 4; ++it){
    int pbase = p0 + it*8;
    if (tid < 8*tc){
      int p = tid / tc, tap = tid % tc;
      int pi = pbase + p;
      int cb = coords[3*pi], cy = coords[3*pi+1], cx = coords[3*pi+2];
      int dy, dx;
      if (g==0){ dy = tap/3 - 1; dx = tap%3 - 1; }
      else if (g==1){ dy = 0; dx = tap - 6; }
      else { dy = tap - 6; dx = 0; }
      int ny = cy+dy, nx = cx+dx;
      int v = -1;
      if (ny>=0 && ny<SY && nx>=0 && nx<SX) v = dense[(cb*SY+ny)*SX + nx];
      nid[p*13 + tap] = v;
    }
    __syncthreads();
    for (int idx = tid; idx < 8*tc*4; idx += 256){
      int ck = idx & 3, rest = idx >> 2;
      int tap = rest % tc, p = rest / tc;
      int v = nid[p*13 + tap];
      uint4 val = make_uint4(0,0,0,0);
      if (v >= 0) val = *(const uint4*)(srcnb + (size_t)v*128 + g*32 + ck*8);
      *(uint4*)(nbf + (p*13+tap)*32 + ck*8) = val;
    }
    __syncthreads();
    {
      int p = tid >> 5, co = tid & 31;
      int pi = pbase + p;
      float acc = 0.f;
      for (int t = 0; t < tc; ++t){
        const short* nr = nbf + (p*13 + t)*32;
        const short* wr = wl + (t*32 + co)*36;
        #pragma unroll
        for (int q = 0; q < 8; ++q){
          uint2 wv = *(const uint2*)(wr + q*4);
          uint2 nv = *(const uint2*)(nr + q*4);
          float2 w0 = bfp2(wv.x), w1 = bfp2(wv.y);
          float2 n0 = bfp2(nv.x), n1 = bfp2(nv.y);
          acc += w0.x*n0.x + w0.y*n0.y;
          acc += w1.x*n1.x + w1.y*n1.y;
        }
      }
      int c = g*32 + co;
      src[(size_t)pi*128 + c] = srcnf[(size_t)pi*128 + c] + acc;
    }
    __syncthreads();
  }
}

// pass-through channels 96..127 (src = 2*srcn), bf16 copy of src, BN2 stats
__global__ __launch_bounds__(256) void post_kernel(float* __restrict__ src, const float* __restrict__ srcnf,
                           short* __restrict__ srcb, float* __restrict__ stats){
  __shared__ float ss[128], sq[128];
  int tid = threadIdx.x;
  if (tid < 128){ ss[tid]=0.f; sq[tid]=0.f; }
  __syncthreads();
  int c4 = (tid & 31) * 4;
  float a0=0,a1=0,a2=0,a3=0, q0=0,q1=0,q2=0,q3=0;
  for (int r = blockIdx.x*8 + (tid>>5); r < N_PTS; r += gridDim.x*8){
    size_t base = (size_t)r*128 + c4;
    float4 v;
    if (c4 < 96){
      v = *(const float4*)(src + base);
    } else {
      float4 sn = *(const float4*)(srcnf + base);
      v = make_float4(2.f*sn.x, 2.f*sn.y, 2.f*sn.z, 2.f*sn.w);
      *(float4*)(src + base) = v;
    }
    uint2 h; h.x = fpack2(v.x, v.y); h.y = fpack2(v.z, v.w);
    *(uint2*)(srcb + base) = h;
    a0+=v.x; a1+=v.y; a2+=v.z; a3+=v.w;
    q0+=v.x*v.x; q1+=v.y*v.y; q2+=v.z*v.z; q3+=v.w*v.w;
  }
  atomicAdd(&ss[c4+0],a0); atomicAdd(&ss[c4+1],a1); atomicAdd(&ss[c4+2],a2); atomicAdd(&ss[c4+3],a3);
  atomicAdd(&sq[c4+0],q0); atomicAdd(&sq[c4+1],q1); atomicAdd(&sq[c4+2],q2); atomicAdd(&sq[c4+3],q3);
  __syncthreads();
  if (tid < 128){
    atomicAdd(&stats[tid],     ss[tid]);
    atomicAdd(&stats[128+tid], sq[tid]);
  }
}

// ---------------- launcher ----------------
extern "C" void kernel_launch(void* const* d_in, const int* in_sizes, int n_in,
                              void* d_out, int out_size, void* d_ws, size_t ws_size,
                              hipStream_t stream)
{
  const float* feats    = (const float*)d_in[0];
  const int*   coords   = (const int*)d_in[1];
  const float* qkv_w    = (const float*)d_in[2];
  const float* fc_out_w = (const float*)d_in[3];
  const float* fc_out_b = (const float*)d_in[4];
  const float* norm0_g  = (const float*)d_in[5];
  const float* norm0_b  = (const float*)d_in[6];
  const float* bn1_g    = (const float*)d_in[7];
  const float* bn1_b    = (const float*)d_in[8];
  const float* bn2_g    = (const float*)d_in[9];
  const float* bn2_b    = (const float*)d_in[10];
  const float* convk_w  = (const float*)d_in[11];
  const float* convh_w  = (const float*)d_in[12];
  const float* convw_w  = (const float*)d_in[13];
  const float* fc1_w    = (const float*)d_in[14];
  const float* fc1_b    = (const float*)d_in[15];
  const float* fc2_w    = (const float*)d_in[16];
  const float* fc2_b    = (const float*)d_in[17];
  float* out = (float*)d_out;
  char* ws = (char*)d_ws;

  int*   sorted = (int*)(ws + OFF_SORTED);
  int*   slot   = (int*)(ws + OFF_SLOT);
  int*   cnt    = (int*)(ws + OFF_CNT);
  int*   offs   = (int*)(ws + OFF_OFFS);
  float* stats0 = (float*)(ws + OFF_STATS);
  float* stats1 = stats0 + 256;
  float* stats2 = stats0 + 512;
  float* sb0    = (float*)(ws + OFF_SB);
  float* sb1    = sb0 + 256;
  float* sb2    = sb0 + 512;
  float* bqkv   = (float*)(ws + OFF_BQKV);
  float* b1     = (float*)(ws + OFF_B1);
  short* wqkv   = (short*)(ws + OFF_WQKV);
  short* wout   = (short*)(ws + OFF_WOUT);
  short* w1     = (short*)(ws + OFF_W1);
  short* w2     = (short*)(ws + OFF_W2);
  short* wconv  = (short*)(ws + OFF_WCONV);
  int*   dense  = (int*)(ws + OFF_DENSE);
  short* qkvb   = (short*)(ws + OFF_QKV);
  float* srcf   = (float*)(ws + OFF_SRC);
  short* srcb   = (short*)(ws + OFF_SRCB);
  short* att    = (short*)(ws + OFF_ATT);
  short* srcnb  = (short*)(ws + OFF_SRCNB);
  float* feats2 = (float*)(ws + OFF_F2);
  short* Hbuf   = (short*)(ws + OFF_H);
  float* srcnf  = (float*)(ws + OFF_SRCNF);

  // init (ws is poisoned 0xAA before every timed launch)
  fill_i32<<<(NSLOT+255)/256, 256, 0, stream>>>(slot, -1, NSLOT);
  fill_i32<<<(NDENSE+255)/256, 256, 0, stream>>>(dense, -1, NDENSE);
  fill_i32<<<3, 256, 0, stream>>>((int*)stats0, 0, 768);

  // window counting-sort (keys are unique)
  keys_kernel<<<(N_PTS+255)/256, 256, 0, stream>>>(coords, slot);
  wincount_kernel<<<(NWIN+255)/256, 256, 0, stream>>>(slot, cnt);
  scan_kernel<<<1, 256, 0, stream>>>(cnt, offs);
  scatter_kernel<<<(NWIN+255)/256, 256, 0, stream>>>(slot, offs, sorted);
  dense_kernel<<<(N_PTS+255)/256, 256, 0, stream>>>(coords, dense);

  // BN0 folded into qkv weights
  bnstats_kernel<<<512, 256, 0, stream>>>(feats, stats0);
  bnfinish_kernel<<<1, 128, 0, stream>>>(stats0, norm0_g, norm0_b, sb0);
  packw_kernel<<<(128*384+255)/256, 256, 0, stream>>>(qkv_w, sb0, wqkv, 128, 384);
  packbias_kernel<<<2, 256, 0, stream>>>(qkv_w, sb0+128, nullptr, bqkv, 128, 384);
  packw_kernel<<<(128*128+255)/256, 256, 0, stream>>>(fc_out_w, nullptr, wout, 128, 128);

  // qkv gemm (gathered rows) -> attention -> fc_out (+residual scatter)
  gemm_kernel<128,0,0><<<dim3(768,3), 256, 32768, stream>>>(feats, nullptr, sorted, wqkv, bqkv, nullptr, nullptr, qkvb, 384);
  attn_kernel<<<768, 256, 131072, stream>>>(qkvb, att);
  gemm_kernel<128,1,1><<<dim3(768,1), 256, 32768, stream>>>(nullptr, att, sorted, wout, fc_out_b, feats, feats2, nullptr, 128);

  // BN1 -> srcn (fp32 + bf16)
  bnstats_kernel<<<512, 256, 0, stream>>>(feats2, stats1);
  bnfinish_kernel<<<1, 128, 0, stream>>>(stats1, bn1_g, bn1_b, sb1);
  srcn_kernel<<<(N_PTS*32+255)/256, 256, 0, stream>>>(feats2, sb1, srcnf, srcnb);

  // convs -> src, BN2 stats
  packconv_kernel<<<(35*1024+255)/256, 256, 0, stream>>>(convk_w, convh_w, convw_w, wconv);
  conv_kernel<<<dim3(N_PTS/32, 3), 256, 37024, stream>>>(wconv, srcnb, srcnf, dense, coords, srcf);
  post_kernel<<<512, 256, 0, stream>>>(srcf, srcnf, srcb, stats2);
  bnfinish_kernel<<<1, 128, 0, stream>>>(stats2, bn2_g, bn2_b, sb2);

  // MLP with BN2 folded into fc1
  packw_kernel<<<(128*256+255)/256, 256, 0, stream>>>(fc1_w, sb2, w1, 128, 256);
  packbias_kernel<<<1, 256, 0, stream>>>(fc1_w, sb2+128, fc1_b, b1, 128, 256);
  packw_kernel<<<(256*128+255)/256, 256, 0, stream>>>(fc2_w, nullptr, w2, 256, 128);

  gemm_kernel<128,1,2><<<dim3(768,2), 256, 32768, stream>>>(nullptr, srcb, nullptr, w1, b1, nullptr, nullptr, Hbuf, 256);
  gemm_kernel<256,1,3><<<dim3(768,1), 256, 65536, stream>>>(nullptr, Hbuf, nullptr, w2, fc2_b, srcf, out, nullptr, 128);

  (void)in_sizes; (void)n_in; (void)out_size; (void)ws_size;
}

// Round 3
// 722.889 us; speedup vs baseline: 1.3522x; 1.3522x over previous
//
#include <hip/hip_runtime.h>

// ---------------- problem constants ----------------
#define N_PTS 98304
#define SY 468
#define SX 468
#define WIN 12
#define MWY 40
#define PER 1600          // mwx*mwy = 40*40
#define NWIN 3200         // B*PER
#define NSLOT (NWIN*144)
#define NDENSE (2*SY*SX)
#define CPB 32            // conv points per block

using bf16x8 = __attribute__((ext_vector_type(8))) short;
using f32x4  = __attribute__((ext_vector_type(4))) float;

__device__ __forceinline__ unsigned short f2bf(float f){
  unsigned u = __float_as_uint(f);
  u += 0x7fffu + ((u>>16)&1u);          // RNE
  return (unsigned short)(u>>16);
}
__device__ __forceinline__ float2 bfp2(unsigned u){
  float2 r; r.x = __uint_as_float(u<<16); r.y = __uint_as_float(u & 0xffff0000u); return r;
}
__device__ __forceinline__ unsigned fpack2(float a, float b){
  return (unsigned)f2bf(a) | ((unsigned)f2bf(b)<<16);
}

// ---------------- workspace layout (bytes) ----------------
constexpr size_t OFF_SORTED = 0;
constexpr size_t OFF_SLOT   = OFF_SORTED + (size_t)N_PTS*4;
constexpr size_t OFF_CNT    = OFF_SLOT + (size_t)NSLOT*4;
constexpr size_t OFF_OFFS   = OFF_CNT + (size_t)NWIN*4;
constexpr size_t OFF_STATS  = OFF_OFFS + (size_t)NWIN*4;     // 3 x (sum[128],sumsq[128])
constexpr size_t OFF_SB     = OFF_STATS + 3*256*4;           // 3 x (scale[128],bias[128])
constexpr size_t OFF_BQKV   = OFF_SB + 3*256*4;              // float[384] (padded)
constexpr size_t OFF_B1     = OFF_BQKV + 512*4;              // float[256]
constexpr size_t OFF_WQKV   = OFF_B1 + 256*4;                // bf16 128x384 packed
constexpr size_t OFF_WOUT   = OFF_WQKV + (size_t)128*384*2;
constexpr size_t OFF_W1     = OFF_WOUT + (size_t)128*128*2;
constexpr size_t OFF_W2     = OFF_W1 + (size_t)128*256*2;
constexpr size_t OFF_WCONV  = OFF_W2 + (size_t)256*128*2;    // bf16 MFMA fragments [35][2][64][8]
constexpr size_t OFF_DENSE  = OFF_WCONV + (size_t)35*1024*2;
constexpr size_t OFF_QKV    = (OFF_DENSE + (size_t)NDENSE*4 + 255) & ~(size_t)255; // qkv bf16 Nx384
constexpr size_t OFF_SRC    = OFF_QKV;                        // (reuse) src fp32 Nx128
constexpr size_t OFF_SRCB   = OFF_QKV + (size_t)N_PTS*128*4;  // (reuse) src bf16 Nx128
constexpr size_t OFF_ATT    = OFF_QKV + (size_t)N_PTS*384*2;  // attout bf16 Nx128
constexpr size_t OFF_SRCNB  = OFF_ATT;                        // (reuse) srcn bf16
constexpr size_t OFF_F2     = OFF_ATT + (size_t)N_PTS*128*2;  // feats2 fp32 Nx128
constexpr size_t OFF_H      = OFF_F2;                         // (reuse) H bf16 Nx256 (same bytes)
constexpr size_t OFF_SRCNF  = OFF_F2 + (size_t)N_PTS*128*4;   // srcn fp32 Nx128
// total ~206 MB

// ---------------- small utility kernels ----------------
__global__ void fill_i32(int* p, int v, int n){
  int i = blockIdx.x*256 + threadIdx.x;
  if (i < n) p[i] = v;
}

__global__ void keys_kernel(const int* __restrict__ coords, int* __restrict__ slot){
  int i = blockIdx.x*256 + threadIdx.x;
  if (i >= N_PTS) return;
  int cb = coords[3*i], cy = coords[3*i+1], cx = coords[3*i+2];
  int w = cb*PER + (cx/WIN)*MWY + (cy/WIN);
  int sub = (cx%WIN)*WIN + (cy%WIN);
  slot[w*144 + sub] = i;         // keys unique -> no collision
}

__global__ void wincount_kernel(const int* __restrict__ slot, int* __restrict__ cnt){
  int w = blockIdx.x*256 + threadIdx.x;
  if (w >= NWIN) return;
  int c = 0;
  for (int s = 0; s < 144; ++s) c += (slot[w*144+s] >= 0);
  cnt[w] = c;
}

__global__ void scan_kernel(const int* __restrict__ cnt, int* __restrict__ offs){
  __shared__ int tsum[256];
  int tid = threadIdx.x;
  int loc[13]; int s = 0;
  #pragma unroll
  for (int j = 0; j < 13; ++j){
    int idx = tid*13 + j;
    int v = (idx < NWIN) ? cnt[idx] : 0;
    loc[j] = s; s += v;
  }
  tsum[tid] = s;
  __syncthreads();
  for (int off = 1; off < 256; off <<= 1){
    int v = (tid >= off) ? tsum[tid-off] : 0;
    __syncthreads();
    tsum[tid] += v;
    __syncthreads();
  }
  int pre = (tid > 0) ? tsum[tid-1] : 0;
  #pragma unroll
  for (int j = 0; j < 13; ++j){
    int idx = tid*13 + j;
    if (idx < NWIN) offs[idx] = pre + loc[j];
  }
}

__global__ void scatter_kernel(const int* __restrict__ slot, const int* __restrict__ offs,
                               int* __restrict__ sorted){
  int w = blockIdx.x*256 + threadIdx.x;
  if (w >= NWIN) return;
  int o = offs[w];
  for (int s = 0; s < 144; ++s){
    int v = slot[w*144+s];
    if (v >= 0) sorted[o++] = v;
  }
}

__global__ void dense_kernel(const int* __restrict__ coords, int* __restrict__ dense){
  int i = blockIdx.x*256 + threadIdx.x;
  if (i >= N_PTS) return;
  dense[(coords[3*i]*SY + coords[3*i+1])*SX + coords[3*i+2]] = i;
}

__global__ __launch_bounds__(256) void bnstats_kernel(const float* __restrict__ x, float* __restrict__ stats){
  __shared__ float sh[256], shq[256];
  int tid = threadIdx.x;
  int c = tid & 127;
  float s = 0.f, q = 0.f;
  for (int r = blockIdx.x*2 + (tid>>7); r < N_PTS; r += gridDim.x*2){
    float v = x[(size_t)r*128 + c];
    s += v; q += v*v;
  }
  sh[tid] = s; shq[tid] = q;
  __syncthreads();
  if (tid < 128){
    atomicAdd(&stats[tid],     sh[tid] + sh[tid+128]);
    atomicAdd(&stats[128+tid], shq[tid] + shq[tid+128]);
  }
}

__global__ void bnfinish_kernel(const float* __restrict__ stats, const float* __restrict__ g,
                                const float* __restrict__ b, float* __restrict__ sb){
  int c = threadIdx.x;
  if (c >= 128) return;
  float mean = stats[c] * (1.0f/N_PTS);
  float var  = stats[128+c] * (1.0f/N_PTS) - mean*mean;
  float s = g[c] * rsqrtf(var + 1e-3f);
  sb[c] = s;
  sb[128+c] = b[c] - mean*s;
}

// pack W (row-major KxN, fp32) into per-lane MFMA B-fragment order, bf16.
// index = (((np*KT + kt)*8 + jt)*64 + lane)*8 + e  ->  W[kt*32 + (lane>>4)*8 + e][np*128 + jt*16 + (lane&15)]
__global__ void packw_kernel(const float* __restrict__ W, const float* __restrict__ scale,
                             short* __restrict__ out, int K, int Nn){
  int t = blockIdx.x*256 + threadIdx.x;
  if (t >= K*Nn) return;
  int e = t & 7, l = (t>>3) & 63, jt = (t>>9) & 7;
  int rest = t >> 12;
  int KT = K >> 5;
  int kt = rest % KT, np = rest / KT;
  int k = kt*32 + ((l>>4)<<3) + e;
  int col = np*128 + jt*16 + (l&15);
  float v = W[(size_t)k*Nn + col];
  if (scale) v *= scale[k];
  out[t] = (short)f2bf(v);
}

__global__ void packbias_kernel(const float* __restrict__ W, const float* __restrict__ bvec,
                                const float* __restrict__ base, float* __restrict__ out, int K, int Nn){
  int o = blockIdx.x*256 + threadIdx.x;
  if (o >= Nn) return;
  float s = base ? base[o] : 0.f;
  for (int k = 0; k < K; ++k) s += bvec[k] * W[(size_t)k*Nn + o];
  out[o] = s;
}

// pack conv weights into MFMA B-fragments: frag[tap][jt][lane][e] = W[tap][ci=(l>>4)*8+e][co=jt*16+(l&15)]
__global__ void packconv_kernel(const float* __restrict__ wk, const float* __restrict__ wh,
                                const float* __restrict__ ww, short* __restrict__ out){
  int t = blockIdx.x*256 + threadIdx.x;
  if (t >= 35*2*64*8) return;
  int e = t & 7, l = (t>>3) & 63, jt = (t>>9) & 1, tap = t >> 10;
  int ci = ((l>>4)<<3) + e;
  int co = jt*16 + (l&15);
  float v;
  if (tap < 9)       v = wk[((size_t)(tap*32) + ci)*32 + co];
  else if (tap < 22) v = wh[((size_t)((tap-9)*32) + ci)*32 + co];
  else               v = ww[((size_t)((tap-22)*32) + ci)*32 + co];
  out[t] = (short)f2bf(v);
}

__global__ __launch_bounds__(256) void srcn_kernel(const float* __restrict__ f2, const float* __restrict__ sb,
                            float* __restrict__ sf, short* __restrict__ sbuf){
  size_t i = (size_t)blockIdx.x*256 + threadIdx.x;
  if (i >= (size_t)N_PTS*32) return;
  int c4 = ((int)(i & 31)) * 4;
  float4 v = ((const float4*)f2)[i];
  float4 o;
  o.x = v.x*sb[c4+0] + sb[128+c4+0];
  o.y = v.y*sb[c4+1] + sb[128+c4+1];
  o.z = v.z*sb[c4+2] + sb[128+c4+2];
  o.w = v.w*sb[c4+3] + sb[128+c4+3];
  ((float4*)sf)[i] = o;
  uint2 h; h.x = fpack2(o.x, o.y); h.y = fpack2(o.z, o.w);
  ((uint2*)sbuf)[i] = h;
}

// ---------------- generic 128-row-tile MFMA GEMM ----------------
// AMODE 0: A rows gathered from fp32 via sorted[]   AMODE 1: A rows direct bf16 (stride K)
// EPI 0: store bf16 (stride dstStride, +bias)
// EPI 1: feats2[sorted[row]] = addf[sorted[row]] + acc + bias   (fc_out + residual scatter)
// EPI 2: relu then store bf16
// EPI 3: outf[row] = addf[row] + acc + bias (fp32, stride 128)
template<int K, int AMODE, int EPI>
__global__ __launch_bounds__(256) void gemm_kernel(
    const float* __restrict__ Afp, const short* __restrict__ Abf,
    const int* __restrict__ sorted, const short* __restrict__ Wp,
    const float* __restrict__ bias, const float* __restrict__ addf,
    float* __restrict__ outf, short* __restrict__ outb, int dstStride)
{
  extern __shared__ char smem[];   // A tile: 128 x K bf16, XOR-swizzled
  const int m0 = blockIdx.x * 128;
  const int np = blockIdx.y;
  const int tid = threadIdx.x;
  if (AMODE == 0){
    const int CHK = K/4;
    for (int c = tid; c < 128*CHK; c += 256){
      int r = c / CHK, q = c % CHK;
      const float* arow = Afp + (size_t)sorted[m0+r]*K;
      float4 v = ((const float4*)arow)[q];
      int off = r*(K*2) + q*8; off ^= ((r&7)<<4);
      *reinterpret_cast<uint2*>(smem+off) = make_uint2(fpack2(v.x,v.y), fpack2(v.z,v.w));
    }
  } else {
    const int CHK = K/8;
    for (int c = tid; c < 128*CHK; c += 256){
      int r = c / CHK, q = c % CHK;
      uint4 v = ((const uint4*)(Abf + (size_t)(m0+r)*K))[q];
      int off = r*(K*2) + q*16; off ^= ((r&7)<<4);
      *reinterpret_cast<uint4*>(smem+off) = v;
    }
  }
  __syncthreads();
  const int w = tid >> 6, l = tid & 63, lg = l >> 4, l16 = l & 15;
  f32x4 zacc; zacc[0]=0.f; zacc[1]=0.f; zacc[2]=0.f; zacc[3]=0.f;
  f32x4 acc[2][8];
  #pragma unroll
  for (int mt=0; mt<2; ++mt)
    #pragma unroll
    for (int jt=0; jt<8; ++jt) acc[mt][jt] = zacc;
  const int KT = K/32;
  #pragma unroll
  for (int kt = 0; kt < KT; ++kt){
    const short* wk = Wp + ((size_t)(np*KT + kt))*4096;
    bf16x8 bfr[8];
    #pragma unroll
    for (int jt=0; jt<8; ++jt)
      bfr[jt] = *reinterpret_cast<const bf16x8*>(wk + jt*512 + l*8);
    #pragma unroll
    for (int mt=0; mt<2; ++mt){
      int row = w*32 + mt*16 + l16;
      int off = row*(K*2) + kt*64 + lg*16; off ^= ((row&7)<<4);
      bf16x8 af = *reinterpret_cast<const bf16x8*>(smem + off);
      #pragma unroll
      for (int jt=0; jt<8; ++jt)
        acc[mt][jt] = __builtin_amdgcn_mfma_f32_16x16x32_bf16(af, bfr[jt], acc[mt][jt], 0, 0, 0);
    }
  }
  #pragma unroll
  for (int mt=0; mt<2; ++mt){
    #pragma unroll
    for (int jt=0; jt<8; ++jt){
      int col = np*128 + jt*16 + l16;
      float bv = bias ? bias[col] : 0.f;
      #pragma unroll
      for (int e=0; e<4; ++e){
        int row = m0 + w*32 + mt*16 + lg*4 + e;
        float v = acc[mt][jt][e] + bv;
        if (EPI == 0){
          outb[(size_t)row*dstStride + col] = (short)f2bf(v);
        } else if (EPI == 1){
          int gi = sorted[row];
          outf[(size_t)gi*128 + col] = addf[(size_t)gi*128 + col] + v;
        } else if (EPI == 2){
          outb[(size_t)row*dstStride + col] = (short)f2bf(fmaxf(v, 0.f));
        } else {
          outf[(size_t)row*128 + col] = addf[(size_t)row*128 + col] + v;
        }
      }
    }
  }
}

// ---------------- fused grouped attention ----------------
// one block per group of 128 sorted tokens; 4 waves, wave w owns query rows [w*32,w*32+32)
__global__ __launch_bounds__(256) void attn_kernel(const short* __restrict__ qkv, short* __restrict__ attout){
  extern __shared__ char smem[];
  char* Qs = smem;            // 128x128 bf16 swizzled
  char* Ks = smem + 32768;
  char* VT = smem + 65536;    // VT[ch][key]
  char* Ps = smem + 98304;    // P, per-wave private rows
  const int g = blockIdx.x;
  const int tid = threadIdx.x;
  for (int c = tid; c < 128*48; c += 256){
    int r = c / 48, q = c % 48;
    uint4 v = ((const uint4*)(qkv + ((size_t)(g*128 + r))*384))[q];
    int ch0 = q*8;
    if (ch0 < 128){
      int off = r*256 + ch0*2; off ^= ((r&7)<<4);
      *reinterpret_cast<uint4*>(Qs + off) = v;
    } else if (ch0 < 256){
      int off = r*256 + (ch0-128)*2; off ^= ((r&7)<<4);
      *reinterpret_cast<uint4*>(Ks + off) = v;
    } else {
      const unsigned short* hv = reinterpret_cast<const unsigned short*>(&v);
      #pragma unroll
      for (int j=0; j<8; ++j){
        int cc = ch0 - 256 + j;
        int off = cc*256 + r*2; off ^= ((cc&7)<<4);
        *reinterpret_cast<unsigned short*>(VT + off) = hv[j];
      }
    }
  }
  __syncthreads();
  const int w = tid>>6, l = tid&63, lg = l>>4, l16 = l&15;
  const int r0 = w*32;
  const float sc = 0.08838834764831845f;  // 1/sqrt(128)
  bf16x8 zero8;
  #pragma unroll
  for (int j=0;j<8;++j) zero8[j]=0;
  f32x4 zacc; zacc[0]=0.f; zacc[1]=0.f; zacc[2]=0.f; zacc[3]=0.f;
  for (int h=0; h<8; ++h){
    f32x4 s[2][8];
    #pragma unroll
    for (int mt=0;mt<2;++mt)
      #pragma unroll
      for (int jt=0;jt<8;++jt) s[mt][jt] = zacc;
    bf16x8 qa[2];
    #pragma unroll
    for (int mt=0; mt<2; ++mt){
      if (lg < 2){                      // K=16 zero-padded to 32
        int row = r0 + mt*16 + l16;
        int off = row*256 + h*32 + lg*16; off ^= ((row&7)<<4);
        qa[mt] = *reinterpret_cast<const bf16x8*>(Qs + off);
      } else qa[mt] = zero8;
    }
    #pragma unroll
    for (int jt=0; jt<8; ++jt){
      bf16x8 kb;
      if (lg < 2){
        int key = jt*16 + l16;
        int off = key*256 + h*32 + lg*16; off ^= ((key&7)<<4);
        kb = *reinterpret_cast<const bf16x8*>(Ks + off);
      } else kb = zero8;
      #pragma unroll
      for (int mt=0; mt<2; ++mt)
        s[mt][jt] = __builtin_amdgcn_mfma_f32_16x16x32_bf16(qa[mt], kb, s[mt][jt], 0,0,0);
    }
    // in-register softmax (row i lives in one 16-lane group, reg e)
    #pragma unroll
    for (int mt=0; mt<2; ++mt){
      #pragma unroll
      for (int e=0; e<4; ++e){
        float m = -1e30f;
        #pragma unroll
        for (int jt=0; jt<8; ++jt){
          float t = s[mt][jt][e] * sc;
          s[mt][jt][e] = t;
          m = fmaxf(m, t);
        }
        #pragma unroll
        for (int off=1; off<16; off<<=1) m = fmaxf(m, __shfl_xor(m, off));
        float d = 0.f;
        #pragma unroll
        for (int jt=0; jt<8; ++jt){
          float p = __expf(s[mt][jt][e] - m);
          s[mt][jt][e] = p; d += p;
        }
        #pragma unroll
        for (int off=1; off<16; off<<=1) d += __shfl_xor(d, off);
        float inv = 1.0f / d;
        #pragma unroll
        for (int jt=0; jt<8; ++jt) s[mt][jt][e] *= inv;
      }
      #pragma unroll
      for (int jt=0; jt<8; ++jt){
        #pragma unroll
        for (int e=0; e<4; ++e){
          int row = r0 + mt*16 + lg*4 + e;
          int off = row*256 + (jt*16 + l16)*2; off ^= ((row&7)<<4);
          *reinterpret_cast<unsigned short*>(Ps + off) = f2bf(s[mt][jt][e]);
        }
      }
    }
    __syncthreads();
    #pragma unroll
    for (int mt=0; mt<2; ++mt){
      f32x4 o = zacc;
      #pragma unroll
      for (int kt=0; kt<4; ++kt){
        int row = r0 + mt*16 + l16;
        int offp = row*256 + kt*64 + lg*16; offp ^= ((row&7)<<4);
        bf16x8 pa = *reinterpret_cast<const bf16x8*>(Ps + offp);
        int cc = h*16 + l16;
        int offv = cc*256 + kt*64 + lg*16; offv ^= ((cc&7)<<4);
        bf16x8 vb = *reinterpret_cast<const bf16x8*>(VT + offv);
        o = __builtin_amdgcn_mfma_f32_16x16x32_bf16(pa, vb, o, 0,0,0);
      }
      #pragma unroll
      for (int e=0; e<4; ++e){
        int row = g*128 + r0 + mt*16 + lg*4 + e;
        attout[(size_t)row*128 + h*16 + l16] = (short)f2bf(o[e]);
      }
    }
    __syncthreads();
  }
}

// ---------------- submanifold convs via MFMA gather-GEMM ----------------
// template G: 0 = 3x3 on ch0:32 (tc=9), 1 = 1x13 on ch32:64, 2 = 13x1 on ch64:96 (tc=13)
// block = 256 threads (4 waves), CPB=32 points. Wave w -> (m-tile = w&1, jt = w>>1).
// LDS nbf: [tc][CPB] slices of 80B (32 bf16 padded to 40), 16B chunks XOR-swizzled by (p&3).
template<int G>
__global__ __launch_bounds__(256) void conv_kernel(
    const short* __restrict__ wfrag, const short* __restrict__ srcnb,
    const float* __restrict__ srcnf, const int* __restrict__ dense,
    const int* __restrict__ coords, float* __restrict__ src)
{
  constexpr int TC   = (G==0) ? 9 : 13;
  constexpr int TAP0 = (G==0) ? 0 : ((G==1) ? 9 : 22);
  __shared__ int scoords[CPB*3];
  __shared__ int nid[CPB*16];
  extern __shared__ char nbf[];
  const int tid = threadIdx.x;
  const int p0 = blockIdx.x * CPB;
  if (tid < CPB*3) scoords[tid] = coords[p0*3 + tid];
  // preload weight fragments (independent of scoords barrier)
  const int w = tid>>6, l = tid&63, lg = l>>4, l16 = l&15;
  const int mt = w & 1, jt = w >> 1;
  bf16x8 bw[TC];
  #pragma unroll
  for (int t = 0; t < TC; ++t)
    bw[t] = *reinterpret_cast<const bf16x8*>(wfrag + (((TAP0+t)*2 + jt)*64 + l)*8);
  __syncthreads();
  for (int i = tid; i < TC*CPB; i += 256){
    int tap = i >> 5, p = i & 31;
    int cb = scoords[p*3], cy = scoords[p*3+1], cx = scoords[p*3+2];
    int dy, dx;
    if (G==0){ dy = tap/3 - 1; dx = tap%3 - 1; }
    else if (G==1){ dy = 0; dx = tap - 6; }
    else { dy = tap - 6; dx = 0; }
    int ny = cy+dy, nx = cx+dx;
    int v = -1;
    if (ny>=0 && ny<SY && nx>=0 && nx<SX) v = dense[(cb*SY+ny)*SX + nx];
    nid[p*16 + tap] = v;
  }
  __syncthreads();
  for (int i = tid; i < TC*CPB*4; i += 256){
    int c = i & 3, s = i >> 2;
    int tap = s >> 5, p = s & 31;
    int v = nid[p*16 + tap];
    uint4 val = make_uint4(0,0,0,0);
    if (v >= 0) val = *(const uint4*)(srcnb + (size_t)v*128 + G*32 + c*8);
    int off = (tap*CPB + p)*80 + ((c*16) ^ ((p&3)<<4));
    *(uint4*)(nbf + off) = val;
  }
  __syncthreads();
  f32x4 acc; acc[0]=0.f; acc[1]=0.f; acc[2]=0.f; acc[3]=0.f;
  const int pA = mt*16 + l16;
  #pragma unroll
  for (int t = 0; t < TC; ++t){
    int off = (t*CPB + pA)*80 + ((lg*16) ^ ((pA&3)<<4));
    bf16x8 af = *reinterpret_cast<const bf16x8*>(nbf + off);
    acc = __builtin_amdgcn_mfma_f32_16x16x32_bf16(af, bw[t], acc, 0, 0, 0);
  }
  #pragma unroll
  for (int e = 0; e < 4; ++e){
    int pi = p0 + mt*16 + lg*4 + e;
    int c = G*32 + jt*16 + l16;
    src[(size_t)pi*128 + c] = srcnf[(size_t)pi*128 + c] + acc[e];
  }
}

// pass-through channels 96..127 (src = 2*srcn), bf16 copy of src, BN2 stats
__global__ __launch_bounds__(256) void post_kernel(float* __restrict__ src, const float* __restrict__ srcnf,
                           short* __restrict__ srcb, float* __restrict__ stats){
  __shared__ float ss[128], sq[128];
  int tid = threadIdx.x;
  if (tid < 128){ ss[tid]=0.f; sq[tid]=0.f; }
  __syncthreads();
  int c4 = (tid & 31) * 4;
  float a0=0,a1=0,a2=0,a3=0, q0=0,q1=0,q2=0,q3=0;
  for (int r = blockIdx.x*8 + (tid>>5); r < N_PTS; r += gridDim.x*8){
    size_t base = (size_t)r*128 + c4;
    float4 v;
    if (c4 < 96){
      v = *(const float4*)(src + base);
    } else {
      float4 sn = *(const float4*)(srcnf + base);
      v = make_float4(2.f*sn.x, 2.f*sn.y, 2.f*sn.z, 2.f*sn.w);
      *(float4*)(src + base) = v;
    }
    uint2 h; h.x = fpack2(v.x, v.y); h.y = fpack2(v.z, v.w);
    *(uint2*)(srcb + base) = h;
    a0+=v.x; a1+=v.y; a2+=v.z; a3+=v.w;
    q0+=v.x*v.x; q1+=v.y*v.y; q2+=v.z*v.z; q3+=v.w*v.w;
  }
  atomicAdd(&ss[c4+0],a0); atomicAdd(&ss[c4+1],a1); atomicAdd(&ss[c4+2],a2); atomicAdd(&ss[c4+3],a3);
  atomicAdd(&sq[c4+0],q0); atomicAdd(&sq[c4+1],q1); atomicAdd(&sq[c4+2],q2); atomicAdd(&sq[c4+3],q3);
  __syncthreads();
  if (tid < 128){
    atomicAdd(&stats[tid],     ss[tid]);
    atomicAdd(&stats[128+tid], sq[tid]);
  }
}

// ---------------- launcher ----------------
extern "C" void kernel_launch(void* const* d_in, const int* in_sizes, int n_in,
                              void* d_out, int out_size, void* d_ws, size_t ws_size,
                              hipStream_t stream)
{
  const float* feats    = (const float*)d_in[0];
  const int*   coords   = (const int*)d_in[1];
  const float* qkv_w    = (const float*)d_in[2];
  const float* fc_out_w = (const float*)d_in[3];
  const float* fc_out_b = (const float*)d_in[4];
  const float* norm0_g  = (const float*)d_in[5];
  const float* norm0_b  = (const float*)d_in[6];
  const float* bn1_g    = (const float*)d_in[7];
  const float* bn1_b    = (const float*)d_in[8];
  const float* bn2_g    = (const float*)d_in[9];
  const float* bn2_b    = (const float*)d_in[10];
  const float* convk_w  = (const float*)d_in[11];
  const float* convh_w  = (const float*)d_in[12];
  const float* convw_w  = (const float*)d_in[13];
  const float* fc1_w    = (const float*)d_in[14];
  const float* fc1_b    = (const float*)d_in[15];
  const float* fc2_w    = (const float*)d_in[16];
  const float* fc2_b    = (const float*)d_in[17];
  float* out = (float*)d_out;
  char* ws = (char*)d_ws;

  int*   sorted = (int*)(ws + OFF_SORTED);
  int*   slot   = (int*)(ws + OFF_SLOT);
  int*   cnt    = (int*)(ws + OFF_CNT);
  int*   offs   = (int*)(ws + OFF_OFFS);
  float* stats0 = (float*)(ws + OFF_STATS);
  float* stats1 = stats0 + 256;
  float* stats2 = stats0 + 512;
  float* sb0    = (float*)(ws + OFF_SB);
  float* sb1    = sb0 + 256;
  float* sb2    = sb0 + 512;
  float* bqkv   = (float*)(ws + OFF_BQKV);
  float* b1     = (float*)(ws + OFF_B1);
  short* wqkv   = (short*)(ws + OFF_WQKV);
  short* wout   = (short*)(ws + OFF_WOUT);
  short* w1     = (short*)(ws + OFF_W1);
  short* w2     = (short*)(ws + OFF_W2);
  short* wconv  = (short*)(ws + OFF_WCONV);
  int*   dense  = (int*)(ws + OFF_DENSE);
  short* qkvb   = (short*)(ws + OFF_QKV);
  float* srcf   = (float*)(ws + OFF_SRC);
  short* srcb   = (short*)(ws + OFF_SRCB);
  short* att    = (short*)(ws + OFF_ATT);
  short* srcnb  = (short*)(ws + OFF_SRCNB);
  float* feats2 = (float*)(ws + OFF_F2);
  short* Hbuf   = (short*)(ws + OFF_H);
  float* srcnf  = (float*)(ws + OFF_SRCNF);

  // init (ws is poisoned 0xAA before every timed launch)
  fill_i32<<<(NSLOT+255)/256, 256, 0, stream>>>(slot, -1, NSLOT);
  fill_i32<<<(NDENSE+255)/256, 256, 0, stream>>>(dense, -1, NDENSE);
  fill_i32<<<3, 256, 0, stream>>>((int*)stats0, 0, 768);

  // window counting-sort (keys are unique)
  keys_kernel<<<(N_PTS+255)/256, 256, 0, stream>>>(coords, slot);
  wincount_kernel<<<(NWIN+255)/256, 256, 0, stream>>>(slot, cnt);
  scan_kernel<<<1, 256, 0, stream>>>(cnt, offs);
  scatter_kernel<<<(NWIN+255)/256, 256, 0, stream>>>(slot, offs, sorted);
  dense_kernel<<<(N_PTS+255)/256, 256, 0, stream>>>(coords, dense);

  // BN0 folded into qkv weights
  bnstats_kernel<<<512, 256, 0, stream>>>(feats, stats0);
  bnfinish_kernel<<<1, 128, 0, stream>>>(stats0, norm0_g, norm0_b, sb0);
  packw_kernel<<<(128*384+255)/256, 256, 0, stream>>>(qkv_w, sb0, wqkv, 128, 384);
  packbias_kernel<<<2, 256, 0, stream>>>(qkv_w, sb0+128, nullptr, bqkv, 128, 384);
  packw_kernel<<<(128*128+255)/256, 256, 0, stream>>>(fc_out_w, nullptr, wout, 128, 128);

  // qkv gemm (gathered rows) -> attention -> fc_out (+residual scatter)
  gemm_kernel<128,0,0><<<dim3(768,3), 256, 32768, stream>>>(feats, nullptr, sorted, wqkv, bqkv, nullptr, nullptr, qkvb, 384);
  attn_kernel<<<768, 256, 131072, stream>>>(qkvb, att);
  gemm_kernel<128,1,1><<<dim3(768,1), 256, 32768, stream>>>(nullptr, att, sorted, wout, fc_out_b, feats, feats2, nullptr, 128);

  // BN1 -> srcn (fp32 + bf16)
  bnstats_kernel<<<512, 256, 0, stream>>>(feats2, stats1);
  bnfinish_kernel<<<1, 128, 0, stream>>>(stats1, bn1_g, bn1_b, sb1);
  srcn_kernel<<<(N_PTS*32+255)/256, 256, 0, stream>>>(feats2, sb1, srcnf, srcnb);

  // convs -> src (MFMA gather-GEMM), then BN2 stats
  packconv_kernel<<<(35*2*64*8+255)/256, 256, 0, stream>>>(convk_w, convh_w, convw_w, wconv);
  conv_kernel<0><<<N_PTS/CPB, 256,  9*CPB*80, stream>>>(wconv, srcnb, srcnf, dense, coords, srcf);
  conv_kernel<1><<<N_PTS/CPB, 256, 13*CPB*80, stream>>>(wconv, srcnb, srcnf, dense, coords, srcf);
  conv_kernel<2><<<N_PTS/CPB, 256, 13*CPB*80, stream>>>(wconv, srcnb, srcnf, dense, coords, srcf);
  post_kernel<<<512, 256, 0, stream>>>(srcf, srcnf, srcb, stats2);
  bnfinish_kernel<<<1, 128, 0, stream>>>(stats2, bn2_g, bn2_b, sb2);

  // MLP with BN2 folded into fc1
  packw_kernel<<<(128*256+255)/256, 256, 0, stream>>>(fc1_w, sb2, w1, 128, 256);
  packbias_kernel<<<1, 256, 0, stream>>>(fc1_w, sb2+128, fc1_b, b1, 128, 256);
  packw_kernel<<<(256*128+255)/256, 256, 0, stream>>>(fc2_w, nullptr, w2, 256, 128);

  gemm_kernel<128,1,2><<<dim3(768,2), 256, 32768, stream>>>(nullptr, srcb, nullptr, w1, b1, nullptr, nullptr, Hbuf, 256);
  gemm_kernel<256,1,3><<<dim3(768,1), 256, 65536, stream>>>(nullptr, Hbuf, nullptr, w2, fc2_b, srcf, out, nullptr, 128);

  (void)in_sizes; (void)n_in; (void)out_size; (void)ws_size;
}

// Round 5
// 646.860 us; speedup vs baseline: 1.5111x; 1.1175x over previous
//
#include <hip/hip_runtime.h>

// ---------------- problem constants ----------------
#define N_PTS 98304
#define SY 468
#define SX 468
#define WIN 12
#define MWY 40
#define PER 1600          // mwx*mwy = 40*40
#define NWIN 3200         // B*PER
#define NSLOT (NWIN*144)
#define NDENSE (2*SY*SX)
#define CPB 32            // conv points per block

using bf16x8 = __attribute__((ext_vector_type(8))) short;
using bf16x4 = __attribute__((ext_vector_type(4))) short;
using f32x4  = __attribute__((ext_vector_type(4))) float;

__device__ __forceinline__ unsigned short f2bf(float f){
  unsigned u = __float_as_uint(f);
  u += 0x7fffu + ((u>>16)&1u);          // RNE
  return (unsigned short)(u>>16);
}
__device__ __forceinline__ float2 bfp2(unsigned u){
  float2 r; r.x = __uint_as_float(u<<16); r.y = __uint_as_float(u & 0xffff0000u); return r;
}
__device__ __forceinline__ unsigned fpack2(float a, float b){
  return (unsigned)f2bf(a) | ((unsigned)f2bf(b)<<16);
}

// K=16 bf16 MFMA (16x16x16): A/B = 4 bf16 (2 VGPR), C/D = 4 f32.
__device__ __forceinline__ f32x4 mfma16(bf16x4 a, bf16x4 b, f32x4 c){
#if __has_builtin(__builtin_amdgcn_mfma_f32_16x16x16bf16_1k)
  return __builtin_amdgcn_mfma_f32_16x16x16bf16_1k(a, b, c, 0, 0, 0);
#else
  asm volatile("v_mfma_f32_16x16x16_bf16 %0, %1, %2, %0\n\ts_nop 7\n\ts_nop 7"
               : "+v"(c) : "v"(a), "v"(b));
  return c;
#endif
}

// ---------------- workspace layout (bytes) ----------------
constexpr size_t OFF_SORTED = 0;
constexpr size_t OFF_SLOT   = OFF_SORTED + (size_t)N_PTS*4;
constexpr size_t OFF_CNT    = OFF_SLOT + (size_t)NSLOT*4;
constexpr size_t OFF_OFFS   = OFF_CNT + (size_t)NWIN*4;
constexpr size_t OFF_STATS  = OFF_OFFS + (size_t)NWIN*4;     // 3 x (sum[128],sumsq[128])
constexpr size_t OFF_SB     = OFF_STATS + 3*256*4;           // 3 x (scale[128],bias[128])
constexpr size_t OFF_BQKV   = OFF_SB + 3*256*4;              // float[384] (padded)
constexpr size_t OFF_B1     = OFF_BQKV + 512*4;              // float[256]
constexpr size_t OFF_WQKV   = OFF_B1 + 256*4;                // bf16 128x384 packed
constexpr size_t OFF_WOUT   = OFF_WQKV + (size_t)128*384*2;
constexpr size_t OFF_W1     = OFF_WOUT + (size_t)128*128*2;
constexpr size_t OFF_W2     = OFF_W1 + (size_t)128*256*2;
constexpr size_t OFF_WCONV  = OFF_W2 + (size_t)256*128*2;    // bf16 MFMA fragments [35][2][64][8]
constexpr size_t OFF_DENSE  = OFF_WCONV + (size_t)35*1024*2;
constexpr size_t OFF_QKV    = (OFF_DENSE + (size_t)NDENSE*4 + 255) & ~(size_t)255; // qkv bf16 Nx384
constexpr size_t OFF_SRC    = OFF_QKV;                        // (reuse) src fp32 Nx128
constexpr size_t OFF_SRCB   = OFF_QKV + (size_t)N_PTS*128*4;  // (reuse) src bf16 Nx128
constexpr size_t OFF_ATT    = OFF_QKV + (size_t)N_PTS*384*2;  // attout bf16 Nx128
constexpr size_t OFF_SRCNB  = OFF_ATT;                        // (reuse) srcn bf16
constexpr size_t OFF_F2     = OFF_ATT + (size_t)N_PTS*128*2;  // feats2 fp32 Nx128
constexpr size_t OFF_H      = OFF_F2;                         // (reuse) H bf16 Nx256 (same bytes)
constexpr size_t OFF_SRCNF  = OFF_F2 + (size_t)N_PTS*128*4;   // srcn fp32 Nx128
// total ~206 MB

// ---------------- small utility kernels ----------------
__global__ void fill_i32(int* p, int v, int n){
  int i = blockIdx.x*256 + threadIdx.x;
  if (i < n) p[i] = v;
}

__global__ void keys_kernel(const int* __restrict__ coords, int* __restrict__ slot){
  int i = blockIdx.x*256 + threadIdx.x;
  if (i >= N_PTS) return;
  int cb = coords[3*i], cy = coords[3*i+1], cx = coords[3*i+2];
  int w = cb*PER + (cx/WIN)*MWY + (cy/WIN);
  int sub = (cx%WIN)*WIN + (cy%WIN);
  slot[w*144 + sub] = i;         // keys unique -> no collision
}

__global__ void wincount_kernel(const int* __restrict__ slot, int* __restrict__ cnt){
  int w = blockIdx.x*256 + threadIdx.x;
  if (w >= NWIN) return;
  int c = 0;
  for (int s = 0; s < 144; ++s) c += (slot[w*144+s] >= 0);
  cnt[w] = c;
}

__global__ void scan_kernel(const int* __restrict__ cnt, int* __restrict__ offs){
  __shared__ int tsum[256];
  int tid = threadIdx.x;
  int loc[13]; int s = 0;
  #pragma unroll
  for (int j = 0; j < 13; ++j){
    int idx = tid*13 + j;
    int v = (idx < NWIN) ? cnt[idx] : 0;
    loc[j] = s; s += v;
  }
  tsum[tid] = s;
  __syncthreads();
  for (int off = 1; off < 256; off <<= 1){
    int v = (tid >= off) ? tsum[tid-off] : 0;
    __syncthreads();
    tsum[tid] += v;
    __syncthreads();
  }
  int pre = (tid > 0) ? tsum[tid-1] : 0;
  #pragma unroll
  for (int j = 0; j < 13; ++j){
    int idx = tid*13 + j;
    if (idx < NWIN) offs[idx] = pre + loc[j];
  }
}

__global__ void scatter_kernel(const int* __restrict__ slot, const int* __restrict__ offs,
                               int* __restrict__ sorted){
  int w = blockIdx.x*256 + threadIdx.x;
  if (w >= NWIN) return;
  int o = offs[w];
  for (int s = 0; s < 144; ++s){
    int v = slot[w*144+s];
    if (v >= 0) sorted[o++] = v;
  }
}

__global__ void dense_kernel(const int* __restrict__ coords, int* __restrict__ dense){
  int i = blockIdx.x*256 + threadIdx.x;
  if (i >= N_PTS) return;
  dense[(coords[3*i]*SY + coords[3*i+1])*SX + coords[3*i+2]] = i;
}

__global__ __launch_bounds__(256) void bnstats_kernel(const float* __restrict__ x, float* __restrict__ stats){
  __shared__ float sh[256], shq[256];
  int tid = threadIdx.x;
  int c = tid & 127;
  float s = 0.f, q = 0.f;
  for (int r = blockIdx.x*2 + (tid>>7); r < N_PTS; r += gridDim.x*2){
    float v = x[(size_t)r*128 + c];
    s += v; q += v*v;
  }
  sh[tid] = s; shq[tid] = q;
  __syncthreads();
  if (tid < 128){
    atomicAdd(&stats[tid],     sh[tid] + sh[tid+128]);
    atomicAdd(&stats[128+tid], shq[tid] + shq[tid+128]);
  }
}

__global__ void bnfinish_kernel(const float* __restrict__ stats, const float* __restrict__ g,
                                const float* __restrict__ b, float* __restrict__ sb){
  int c = threadIdx.x;
  if (c >= 128) return;
  float mean = stats[c] * (1.0f/N_PTS);
  float var  = stats[128+c] * (1.0f/N_PTS) - mean*mean;
  float s = g[c] * rsqrtf(var + 1e-3f);
  sb[c] = s;
  sb[128+c] = b[c] - mean*s;
}

// pack W (row-major KxN, fp32) into per-lane MFMA B-fragment order, bf16.
// index = (((np*KT + kt)*8 + jt)*64 + lane)*8 + e  ->  W[kt*32 + (lane>>4)*8 + e][np*128 + jt*16 + (lane&15)]
__global__ void packw_kernel(const float* __restrict__ W, const float* __restrict__ scale,
                             short* __restrict__ out, int K, int Nn){
  int t = blockIdx.x*256 + threadIdx.x;
  if (t >= K*Nn) return;
  int e = t & 7, l = (t>>3) & 63, jt = (t>>9) & 7;
  int rest = t >> 12;
  int KT = K >> 5;
  int kt = rest % KT, np = rest / KT;
  int k = kt*32 + ((l>>4)<<3) + e;
  int col = np*128 + jt*16 + (l&15);
  float v = W[(size_t)k*Nn + col];
  if (scale) v *= scale[k];
  out[t] = (short)f2bf(v);
}

__global__ void packbias_kernel(const float* __restrict__ W, const float* __restrict__ bvec,
                                const float* __restrict__ base, float* __restrict__ out, int K, int Nn){
  int o = blockIdx.x*256 + threadIdx.x;
  if (o >= Nn) return;
  float s = base ? base[o] : 0.f;
  for (int k = 0; k < K; ++k) s += bvec[k] * W[(size_t)k*Nn + o];
  out[o] = s;
}

// pack conv weights into MFMA B-fragments: frag[tap][jt][lane][e] = W[tap][ci=(l>>4)*8+e][co=jt*16+(l&15)]
__global__ void packconv_kernel(const float* __restrict__ wk, const float* __restrict__ wh,
                                const float* __restrict__ ww, short* __restrict__ out){
  int t = blockIdx.x*256 + threadIdx.x;
  if (t >= 35*2*64*8) return;
  int e = t & 7, l = (t>>3) & 63, jt = (t>>9) & 1, tap = t >> 10;
  int ci = ((l>>4)<<3) + e;
  int co = jt*16 + (l&15);
  float v;
  if (tap < 9)       v = wk[((size_t)(tap*32) + ci)*32 + co];
  else if (tap < 22) v = wh[((size_t)((tap-9)*32) + ci)*32 + co];
  else               v = ww[((size_t)((tap-22)*32) + ci)*32 + co];
  out[t] = (short)f2bf(v);
}

__global__ __launch_bounds__(256) void srcn_kernel(const float* __restrict__ f2, const float* __restrict__ sb,
                            float* __restrict__ sf, short* __restrict__ sbuf){
  size_t i = (size_t)blockIdx.x*256 + threadIdx.x;
  if (i >= (size_t)N_PTS*32) return;
  int c4 = ((int)(i & 31)) * 4;
  float4 v = ((const float4*)f2)[i];
  float4 o;
  o.x = v.x*sb[c4+0] + sb[128+c4+0];
  o.y = v.y*sb[c4+1] + sb[128+c4+1];
  o.z = v.z*sb[c4+2] + sb[128+c4+2];
  o.w = v.w*sb[c4+3] + sb[128+c4+3];
  ((float4*)sf)[i] = o;
  uint2 h; h.x = fpack2(o.x, o.y); h.y = fpack2(o.z, o.w);
  ((uint2*)sbuf)[i] = h;
}

// ---------------- generic 128-row-tile MFMA GEMM ----------------
// AMODE 0: A rows gathered from fp32 via sorted[]   AMODE 1: A rows direct bf16 (stride K)
// EPI 0: store bf16 (stride dstStride, +bias)
// EPI 1: feats2[sorted[row]] = addf[sorted[row]] + acc + bias   (fc_out + residual scatter)
// EPI 2: relu then store bf16
// EPI 3: outf[row] = addf[row] + acc + bias (fp32, stride 128)
template<int K, int AMODE, int EPI>
__global__ __launch_bounds__(256) void gemm_kernel(
    const float* __restrict__ Afp, const short* __restrict__ Abf,
    const int* __restrict__ sorted, const short* __restrict__ Wp,
    const float* __restrict__ bias, const float* __restrict__ addf,
    float* __restrict__ outf, short* __restrict__ outb, int dstStride)
{
  extern __shared__ char smem[];   // A tile: 128 x K bf16, XOR-swizzled
  const int m0 = blockIdx.x * 128;
  const int np = blockIdx.y;
  const int tid = threadIdx.x;
  if (AMODE == 0){
    const int CHK = K/4;
    for (int c = tid; c < 128*CHK; c += 256){
      int r = c / CHK, q = c % CHK;
      const float* arow = Afp + (size_t)sorted[m0+r]*K;
      float4 v = ((const float4*)arow)[q];
      int off = r*(K*2) + q*8; off ^= ((r&7)<<4);
      *reinterpret_cast<uint2*>(smem+off) = make_uint2(fpack2(v.x,v.y), fpack2(v.z,v.w));
    }
  } else {
    const int CHK = K/8;
    for (int c = tid; c < 128*CHK; c += 256){
      int r = c / CHK, q = c % CHK;
      uint4 v = ((const uint4*)(Abf + (size_t)(m0+r)*K))[q];
      int off = r*(K*2) + q*16; off ^= ((r&7)<<4);
      *reinterpret_cast<uint4*>(smem+off) = v;
    }
  }
  __syncthreads();
  const int w = tid >> 6, l = tid & 63, lg = l >> 4, l16 = l & 15;
  f32x4 zacc; zacc[0]=0.f; zacc[1]=0.f; zacc[2]=0.f; zacc[3]=0.f;
  f32x4 acc[2][8];
  #pragma unroll
  for (int mt=0; mt<2; ++mt)
    #pragma unroll
    for (int jt=0; jt<8; ++jt) acc[mt][jt] = zacc;
  const int KT = K/32;
  #pragma unroll
  for (int kt = 0; kt < KT; ++kt){
    const short* wk = Wp + ((size_t)(np*KT + kt))*4096;
    bf16x8 bfr[8];
    #pragma unroll
    for (int jt=0; jt<8; ++jt)
      bfr[jt] = *reinterpret_cast<const bf16x8*>(wk + jt*512 + l*8);
    #pragma unroll
    for (int mt=0; mt<2; ++mt){
      int row = w*32 + mt*16 + l16;
      int off = row*(K*2) + kt*64 + lg*16; off ^= ((row&7)<<4);
      bf16x8 af = *reinterpret_cast<const bf16x8*>(smem + off);
      #pragma unroll
      for (int jt=0; jt<8; ++jt)
        acc[mt][jt] = __builtin_amdgcn_mfma_f32_16x16x32_bf16(af, bfr[jt], acc[mt][jt], 0, 0, 0);
    }
  }
  #pragma unroll
  for (int mt=0; mt<2; ++mt){
    #pragma unroll
    for (int jt=0; jt<8; ++jt){
      int col = np*128 + jt*16 + l16;
      float bv = bias ? bias[col] : 0.f;
      #pragma unroll
      for (int e=0; e<4; ++e){
        int row = m0 + w*32 + mt*16 + lg*4 + e;
        float v = acc[mt][jt][e] + bv;
        if (EPI == 0){
          outb[(size_t)row*dstStride + col] = (short)f2bf(v);
        } else if (EPI == 1){
          int gi = sorted[row];
          outf[(size_t)gi*128 + col] = addf[(size_t)gi*128 + col] + v;
        } else if (EPI == 2){
          outb[(size_t)row*dstStride + col] = (short)f2bf(fmaxf(v, 0.f));
        } else {
          outf[(size_t)row*128 + col] = addf[(size_t)row*128 + col] + v;
        }
      }
    }
  }
}

// ---------------- fused grouped attention (K=16 MFMA, swapped QK^T) ----------------
// One block per group of 128 sorted tokens; 4 waves; wave w owns q rows [w*32, w*32+32).
// S^T = mfma(K_frag, Q_frag) puts P^T in exactly the A-fragment layout the K=16 PV
// MFMA needs (lane l16 = q, k = lg*4+e = key) -> zero cross-lane P movement, no barriers.
// Only V^T lives in LDS (32 KB, XOR swizzle F=(cc&7)^((cc>>3)&7) de-conflicts both sides).
__global__ __launch_bounds__(256) void attn_kernel(const short* __restrict__ qkv, short* __restrict__ attout){
  __shared__ char VT[32768];     // VT[ch][token] bf16, swizzled
  const int g = blockIdx.x;
  const int tid = threadIdx.x;
  // stage V^T: thread handles token r, channel-octet q
  for (int c = tid; c < 128*16; c += 256){
    int r = c >> 4, q = c & 15;
    uint4 v = *(const uint4*)(qkv + ((size_t)(g*128 + r))*384 + 256 + q*8);
    const unsigned short* hv = (const unsigned short*)&v;
    #pragma unroll
    for (int j = 0; j < 8; ++j){
      int cc = q*8 + j;
      int F = ((cc & 7) ^ ((cc >> 3) & 7)) << 4;
      *(unsigned short*)(VT + cc*256 + ((r*2) ^ F)) = hv[j];
    }
  }
  __syncthreads();
  const int w = tid>>6, l = tid&63, lg = l>>4, l16 = l&15;
  const float sc2 = 0.12751744f;   // (1/sqrt(128)) * log2(e)
  f32x4 z4; z4[0]=0.f; z4[1]=0.f; z4[2]=0.f; z4[3]=0.f;
  const short* qbase = qkv + (size_t)(g*128)*384;
  for (int h = 0; h < 8; ++h){
    const int ch = h*16 + lg*4;
    // Q fragments (B-operand): token = w*32 + mt*16 + l16, 4 ch per lane
    bf16x4 qf0 = *(const bf16x4*)(qbase + (size_t)(w*32 + l16)*384 + ch);
    bf16x4 qf1 = *(const bf16x4*)(qbase + (size_t)(w*32 + 16 + l16)*384 + ch);
    f32x4 s[8][2];
    #pragma unroll
    for (int kb=0; kb<8; ++kb){ s[kb][0] = z4; s[kb][1] = z4; }
    #pragma unroll
    for (int kb=0; kb<8; ++kb){
      bf16x4 kf = *(const bf16x4*)(qbase + (size_t)(kb*16 + l16)*384 + 128 + ch);
      s[kb][0] = mfma16(kf, qf0, s[kb][0]);
      s[kb][1] = mfma16(kf, qf1, s[kb][1]);
    }
    // softmax over keys: lane holds P^T[key=kb*16+lg*4+e][q=l16] -> reduce across lg groups
    float inv0, inv1;
    #pragma unroll
    for (int mt=0; mt<2; ++mt){
      float m = -1e30f;
      #pragma unroll
      for (int kb=0; kb<8; ++kb)
        #pragma unroll
        for (int e=0; e<4; ++e) m = fmaxf(m, s[kb][mt][e]);
      m = fmaxf(m, __shfl_xor(m, 16));
      m = fmaxf(m, __shfl_xor(m, 32));
      float d = 0.f;
      #pragma unroll
      for (int kb=0; kb<8; ++kb)
        #pragma unroll
        for (int e=0; e<4; ++e){
          float p = exp2f((s[kb][mt][e] - m) * sc2);
          s[kb][mt][e] = p; d += p;
        }
      d += __shfl_xor(d, 16);
      d += __shfl_xor(d, 32);
      if (mt == 0) inv0 = 1.0f/d; else inv1 = 1.0f/d;
    }
    // PV: pa is register-local repack; vb from swizzled VT
    f32x4 o0 = z4, o1 = z4;
    const int cc = h*16 + l16;
    const int F = ((cc & 7) ^ ((cc >> 3) & 7)) << 4;
    #pragma unroll
    for (int kb=0; kb<8; ++kb){
      bf16x4 vb = *(const bf16x4*)(VT + cc*256 + ((kb*32 + lg*8) ^ F));
      bf16x4 pa0, pa1;
      #pragma unroll
      for (int e=0; e<4; ++e){
        pa0[e] = (short)f2bf(s[kb][0][e] * inv0);
        pa1[e] = (short)f2bf(s[kb][1][e] * inv1);
      }
      o0 = mfma16(pa0, vb, o0);
      o1 = mfma16(pa1, vb, o1);
    }
    #pragma unroll
    for (int e=0; e<4; ++e){
      int row0 = g*128 + w*32      + lg*4 + e;
      int row1 = g*128 + w*32 + 16 + lg*4 + e;
      attout[(size_t)row0*128 + h*16 + l16] = (short)f2bf(o0[e]);
      attout[(size_t)row1*128 + h*16 + l16] = (short)f2bf(o1[e]);
    }
  }
}

// ---------------- submanifold convs via MFMA gather-GEMM ----------------
// template G: 0 = 3x3 on ch0:32 (tc=9), 1 = 1x13 on ch32:64, 2 = 13x1 on ch64:96 (tc=13)
// block = 256 threads (4 waves), CPB=32 points. Wave w -> (m-tile = w&1, jt = w>>1).
// LDS nbf: [tc][CPB] slices of 80B (32 bf16 padded to 40), 16B chunks XOR-swizzled by (p&3).
template<int G>
__global__ __launch_bounds__(256) void conv_kernel(
    const short* __restrict__ wfrag, const short* __restrict__ srcnb,
    const float* __restrict__ srcnf, const int* __restrict__ dense,
    const int* __restrict__ coords, float* __restrict__ src)
{
  constexpr int TC   = (G==0) ? 9 : 13;
  constexpr int TAP0 = (G==0) ? 0 : ((G==1) ? 9 : 22);
  __shared__ int scoords[CPB*3];
  __shared__ int nid[CPB*16];
  extern __shared__ char nbf[];
  const int tid = threadIdx.x;
  const int p0 = blockIdx.x * CPB;
  if (tid < CPB*3) scoords[tid] = coords[p0*3 + tid];
  // preload weight fragments (independent of scoords barrier)
  const int w = tid>>6, l = tid&63, lg = l>>4, l16 = l&15;
  const int mt = w & 1, jt = w >> 1;
  bf16x8 bw[TC];
  #pragma unroll
  for (int t = 0; t < TC; ++t)
    bw[t] = *reinterpret_cast<const bf16x8*>(wfrag + (((TAP0+t)*2 + jt)*64 + l)*8);
  __syncthreads();
  for (int i = tid; i < TC*CPB; i += 256){
    int tap = i >> 5, p = i & 31;
    int cb = scoords[p*3], cy = scoords[p*3+1], cx = scoords[p*3+2];
    int dy, dx;
    if (G==0){ dy = tap/3 - 1; dx = tap%3 - 1; }
    else if (G==1){ dy = 0; dx = tap - 6; }
    else { dy = tap - 6; dx = 0; }
    int ny = cy+dy, nx = cx+dx;
    int v = -1;
    if (ny>=0 && ny<SY && nx>=0 && nx<SX) v = dense[(cb*SY+ny)*SX + nx];
    nid[p*16 + tap] = v;
  }
  __syncthreads();
  for (int i = tid; i < TC*CPB*4; i += 256){
    int c = i & 3, s = i >> 2;
    int tap = s >> 5, p = s & 31;
    int v = nid[p*16 + tap];
    uint4 val = make_uint4(0,0,0,0);
    if (v >= 0) val = *(const uint4*)(srcnb + (size_t)v*128 + G*32 + c*8);
    int off = (tap*CPB + p)*80 + ((c*16) ^ ((p&3)<<4));
    *(uint4*)(nbf + off) = val;
  }
  __syncthreads();
  f32x4 acc; acc[0]=0.f; acc[1]=0.f; acc[2]=0.f; acc[3]=0.f;
  const int pA = mt*16 + l16;
  #pragma unroll
  for (int t = 0; t < TC; ++t){
    int off = (t*CPB + pA)*80 + ((lg*16) ^ ((pA&3)<<4));
    bf16x8 af = *reinterpret_cast<const bf16x8*>(nbf + off);
    acc = __builtin_amdgcn_mfma_f32_16x16x32_bf16(af, bw[t], acc, 0, 0, 0);
  }
  #pragma unroll
  for (int e = 0; e < 4; ++e){
    int pi = p0 + mt*16 + lg*4 + e;
    int c = G*32 + jt*16 + l16;
    src[(size_t)pi*128 + c] = srcnf[(size_t)pi*128 + c] + acc[e];
  }
}

// pass-through channels 96..127 (src = 2*srcn), bf16 copy of src, BN2 stats
__global__ __launch_bounds__(256) void post_kernel(float* __restrict__ src, const float* __restrict__ srcnf,
                           short* __restrict__ srcb, float* __restrict__ stats){
  __shared__ float ss[128], sq[128];
  int tid = threadIdx.x;
  if (tid < 128){ ss[tid]=0.f; sq[tid]=0.f; }
  __syncthreads();
  int c4 = (tid & 31) * 4;
  float a0=0,a1=0,a2=0,a3=0, q0=0,q1=0,q2=0,q3=0;
  for (int r = blockIdx.x*8 + (tid>>5); r < N_PTS; r += gridDim.x*8){
    size_t base = (size_t)r*128 + c4;
    float4 v;
    if (c4 < 96){
      v = *(const float4*)(src + base);
    } else {
      float4 sn = *(const float4*)(srcnf + base);
      v = make_float4(2.f*sn.x, 2.f*sn.y, 2.f*sn.z, 2.f*sn.w);
      *(float4*)(src + base) = v;
    }
    uint2 h; h.x = fpack2(v.x, v.y); h.y = fpack2(v.z, v.w);
    *(uint2*)(srcb + base) = h;
    a0+=v.x; a1+=v.y; a2+=v.z; a3+=v.w;
    q0+=v.x*v.x; q1+=v.y*v.y; q2+=v.z*v.z; q3+=v.w*v.w;
  }
  atomicAdd(&ss[c4+0],a0); atomicAdd(&ss[c4+1],a1); atomicAdd(&ss[c4+2],a2); atomicAdd(&ss[c4+3],a3);
  atomicAdd(&sq[c4+0],q0); atomicAdd(&sq[c4+1],q1); atomicAdd(&sq[c4+2],q2); atomicAdd(&sq[c4+3],q3);
  __syncthreads();
  if (tid < 128){
    atomicAdd(&stats[tid],     ss[tid]);
    atomicAdd(&stats[128+tid], sq[tid]);
  }
}

// ---------------- launcher ----------------
extern "C" void kernel_launch(void* const* d_in, const int* in_sizes, int n_in,
                              void* d_out, int out_size, void* d_ws, size_t ws_size,
                              hipStream_t stream)
{
  const float* feats    = (const float*)d_in[0];
  const int*   coords   = (const int*)d_in[1];
  const float* qkv_w    = (const float*)d_in[2];
  const float* fc_out_w = (const float*)d_in[3];
  const float* fc_out_b = (const float*)d_in[4];
  const float* norm0_g  = (const float*)d_in[5];
  const float* norm0_b  = (const float*)d_in[6];
  const float* bn1_g    = (const float*)d_in[7];
  const float* bn1_b    = (const float*)d_in[8];
  const float* bn2_g    = (const float*)d_in[9];
  const float* bn2_b    = (const float*)d_in[10];
  const float* convk_w  = (const float*)d_in[11];
  const float* convh_w  = (const float*)d_in[12];
  const float* convw_w  = (const float*)d_in[13];
  const float* fc1_w    = (const float*)d_in[14];
  const float* fc1_b    = (const float*)d_in[15];
  const float* fc2_w    = (const float*)d_in[16];
  const float* fc2_b    = (const float*)d_in[17];
  float* out = (float*)d_out;
  char* ws = (char*)d_ws;

  int*   sorted = (int*)(ws + OFF_SORTED);
  int*   slot   = (int*)(ws + OFF_SLOT);
  int*   cnt    = (int*)(ws + OFF_CNT);
  int*   offs   = (int*)(ws + OFF_OFFS);
  float* stats0 = (float*)(ws + OFF_STATS);
  float* stats1 = stats0 + 256;
  float* stats2 = stats0 + 512;
  float* sb0    = (float*)(ws + OFF_SB);
  float* sb1    = sb0 + 256;
  float* sb2    = sb0 + 512;
  float* bqkv   = (float*)(ws + OFF_BQKV);
  float* b1     = (float*)(ws + OFF_B1);
  short* wqkv   = (short*)(ws + OFF_WQKV);
  short* wout   = (short*)(ws + OFF_WOUT);
  short* w1     = (short*)(ws + OFF_W1);
  short* w2     = (short*)(ws + OFF_W2);
  short* wconv  = (short*)(ws + OFF_WCONV);
  int*   dense  = (int*)(ws + OFF_DENSE);
  short* qkvb   = (short*)(ws + OFF_QKV);
  float* srcf   = (float*)(ws + OFF_SRC);
  short* srcb   = (short*)(ws + OFF_SRCB);
  short* att    = (short*)(ws + OFF_ATT);
  short* srcnb  = (short*)(ws + OFF_SRCNB);
  float* feats2 = (float*)(ws + OFF_F2);
  short* Hbuf   = (short*)(ws + OFF_H);
  float* srcnf  = (float*)(ws + OFF_SRCNF);

  // init (ws is poisoned 0xAA before every timed launch)
  fill_i32<<<(NSLOT+255)/256, 256, 0, stream>>>(slot, -1, NSLOT);
  fill_i32<<<(NDENSE+255)/256, 256, 0, stream>>>(dense, -1, NDENSE);
  fill_i32<<<3, 256, 0, stream>>>((int*)stats0, 0, 768);

  // window counting-sort (keys are unique)
  keys_kernel<<<(N_PTS+255)/256, 256, 0, stream>>>(coords, slot);
  wincount_kernel<<<(NWIN+255)/256, 256, 0, stream>>>(slot, cnt);
  scan_kernel<<<1, 256, 0, stream>>>(cnt, offs);
  scatter_kernel<<<(NWIN+255)/256, 256, 0, stream>>>(slot, offs, sorted);
  dense_kernel<<<(N_PTS+255)/256, 256, 0, stream>>>(coords, dense);

  // BN0 folded into qkv weights
  bnstats_kernel<<<512, 256, 0, stream>>>(feats, stats0);
  bnfinish_kernel<<<1, 128, 0, stream>>>(stats0, norm0_g, norm0_b, sb0);
  packw_kernel<<<(128*384+255)/256, 256, 0, stream>>>(qkv_w, sb0, wqkv, 128, 384);
  packbias_kernel<<<2, 256, 0, stream>>>(qkv_w, sb0+128, nullptr, bqkv, 128, 384);
  packw_kernel<<<(128*128+255)/256, 256, 0, stream>>>(fc_out_w, nullptr, wout, 128, 128);

  // qkv gemm (gathered rows) -> attention -> fc_out (+residual scatter)
  gemm_kernel<128,0,0><<<dim3(768,3), 256, 32768, stream>>>(feats, nullptr, sorted, wqkv, bqkv, nullptr, nullptr, qkvb, 384);
  attn_kernel<<<768, 256, 0, stream>>>(qkvb, att);
  gemm_kernel<128,1,1><<<dim3(768,1), 256, 32768, stream>>>(nullptr, att, sorted, wout, fc_out_b, feats, feats2, nullptr, 128);

  // BN1 -> srcn (fp32 + bf16)
  bnstats_kernel<<<512, 256, 0, stream>>>(feats2, stats1);
  bnfinish_kernel<<<1, 128, 0, stream>>>(stats1, bn1_g, bn1_b, sb1);
  srcn_kernel<<<(N_PTS*32+255)/256, 256, 0, stream>>>(feats2, sb1, srcnf, srcnb);

  // convs -> src (MFMA gather-GEMM), then BN2 stats
  packconv_kernel<<<(35*2*64*8+255)/256, 256, 0, stream>>>(convk_w, convh_w, convw_w, wconv);
  conv_kernel<0><<<N_PTS/CPB, 256,  9*CPB*80, stream>>>(wconv, srcnb, srcnf, dense, coords, srcf);
  conv_kernel<1><<<N_PTS/CPB, 256, 13*CPB*80, stream>>>(wconv, srcnb, srcnf, dense, coords, srcf);
  conv_kernel<2><<<N_PTS/CPB, 256, 13*CPB*80, stream>>>(wconv, srcnb, srcnf, dense, coords, srcf);
  post_kernel<<<512, 256, 0, stream>>>(srcf, srcnf, srcb, stats2);
  bnfinish_kernel<<<1, 128, 0, stream>>>(stats2, bn2_g, bn2_b, sb2);

  // MLP with BN2 folded into fc1
  packw_kernel<<<(128*256+255)/256, 256, 0, stream>>>(fc1_w, sb2, w1, 128, 256);
  packbias_kernel<<<1, 256, 0, stream>>>(fc1_w, sb2+128, fc1_b, b1, 128, 256);
  packw_kernel<<<(256*128+255)/256, 256, 0, stream>>>(fc2_w, nullptr, w2, 256, 128);

  gemm_kernel<128,1,2><<<dim3(768,2), 256, 32768, stream>>>(nullptr, srcb, nullptr, w1, b1, nullptr, nullptr, Hbuf, 256);
  gemm_kernel<256,1,3><<<dim3(768,1), 256, 65536, stream>>>(nullptr, Hbuf, nullptr, w2, fc2_b, srcf, out, nullptr, 128);

  (void)in_sizes; (void)n_in; (void)out_size; (void)ws_size;
}

// Round 6
// 611.804 us; speedup vs baseline: 1.5977x; 1.0573x over previous
//
#include <hip/hip_runtime.h>

// ---------------- problem constants ----------------
#define N_PTS 98304
#define SY 468
#define SX 468
#define WIN 12
#define MWY 40
#define PER 1600          // mwx*mwy = 40*40
#define NWIN 3200         // B*PER
#define NSLOT (NWIN*144)
#define NDENSE (2*SY*SX)
#define CPB 32            // conv points per block

using bf16x8 = __attribute__((ext_vector_type(8))) short;
using bf16x4 = __attribute__((ext_vector_type(4))) short;
using f32x4  = __attribute__((ext_vector_type(4))) float;

__device__ __forceinline__ unsigned short f2bf(float f){
  unsigned u = __float_as_uint(f);
  u += 0x7fffu + ((u>>16)&1u);          // RNE
  return (unsigned short)(u>>16);
}
__device__ __forceinline__ float2 bfp2(unsigned u){
  float2 r; r.x = __uint_as_float(u<<16); r.y = __uint_as_float(u & 0xffff0000u); return r;
}
__device__ __forceinline__ unsigned fpack2(float a, float b){
  return (unsigned)f2bf(a) | ((unsigned)f2bf(b)<<16);
}

// K=16 bf16 MFMA (16x16x16): A/B = 4 bf16 (2 VGPR), C/D = 4 f32.
__device__ __forceinline__ f32x4 mfma16(bf16x4 a, bf16x4 b, f32x4 c){
#if __has_builtin(__builtin_amdgcn_mfma_f32_16x16x16bf16_1k)
  return __builtin_amdgcn_mfma_f32_16x16x16bf16_1k(a, b, c, 0, 0, 0);
#else
  asm volatile("v_mfma_f32_16x16x16_bf16 %0, %1, %2, %0\n\ts_nop 7\n\ts_nop 7"
               : "+v"(c) : "v"(a), "v"(b));
  return c;
#endif
}

// ---------------- workspace layout (bytes) ----------------
constexpr size_t OFF_SORTED = 0;
constexpr size_t OFF_SLOT   = OFF_SORTED + (size_t)N_PTS*4;
constexpr size_t OFF_CNT    = OFF_SLOT + (size_t)NSLOT*4;
constexpr size_t OFF_OFFS   = OFF_CNT + (size_t)NWIN*4;
constexpr size_t OFF_STATS  = OFF_OFFS + (size_t)NWIN*4;     // 3 x (sum[128],sumsq[128])
constexpr size_t OFF_SB     = OFF_STATS + 3*256*4;           // 3 x (scale[128],bias[128])
constexpr size_t OFF_BQKV   = OFF_SB + 3*256*4;              // float[384] (padded)
constexpr size_t OFF_B1     = OFF_BQKV + 512*4;              // float[256]
constexpr size_t OFF_WQKV   = OFF_B1 + 256*4;                // bf16 128x384 packed
constexpr size_t OFF_WOUT   = OFF_WQKV + (size_t)128*384*2;
constexpr size_t OFF_W1     = OFF_WOUT + (size_t)128*128*2;
constexpr size_t OFF_W2     = OFF_W1 + (size_t)128*256*2;
constexpr size_t OFF_WCONV  = OFF_W2 + (size_t)256*128*2;    // bf16 MFMA fragments [35][2][64][8]
constexpr size_t OFF_DENSE  = OFF_WCONV + (size_t)35*1024*2;
constexpr size_t OFF_QKV    = (OFF_DENSE + (size_t)NDENSE*4 + 255) & ~(size_t)255; // qkv bf16 blocked [768][24][128][16]
constexpr size_t OFF_SRC    = OFF_QKV;                        // (reuse) src fp32 Nx128
constexpr size_t OFF_SRCB   = OFF_QKV + (size_t)N_PTS*128*4;  // (reuse) src bf16 Nx128
constexpr size_t OFF_ATT    = OFF_QKV + (size_t)N_PTS*384*2;  // attout bf16 Nx128
constexpr size_t OFF_SRCNB  = OFF_ATT;                        // (reuse) srcn bf16
constexpr size_t OFF_F2     = OFF_ATT + (size_t)N_PTS*128*2;  // feats2 fp32 Nx128
constexpr size_t OFF_H      = OFF_F2;                         // (reuse) H bf16 Nx256 (same bytes)
// total ~155 MB

// ---------------- small utility kernels ----------------
__global__ void fill_i32(int* p, int v, int n){
  int i = blockIdx.x*256 + threadIdx.x;
  if (i < n) p[i] = v;
}

__global__ void keys_kernel(const int* __restrict__ coords, int* __restrict__ slot){
  int i = blockIdx.x*256 + threadIdx.x;
  if (i >= N_PTS) return;
  int cb = coords[3*i], cy = coords[3*i+1], cx = coords[3*i+2];
  int w = cb*PER + (cx/WIN)*MWY + (cy/WIN);
  int sub = (cx%WIN)*WIN + (cy%WIN);
  slot[w*144 + sub] = i;         // keys unique -> no collision
}

__global__ void wincount_kernel(const int* __restrict__ slot, int* __restrict__ cnt){
  int w = blockIdx.x*256 + threadIdx.x;
  if (w >= NWIN) return;
  int c = 0;
  for (int s = 0; s < 144; ++s) c += (slot[w*144+s] >= 0);
  cnt[w] = c;
}

__global__ void scan_kernel(const int* __restrict__ cnt, int* __restrict__ offs){
  __shared__ int tsum[256];
  int tid = threadIdx.x;
  int loc[13]; int s = 0;
  #pragma unroll
  for (int j = 0; j < 13; ++j){
    int idx = tid*13 + j;
    int v = (idx < NWIN) ? cnt[idx] : 0;
    loc[j] = s; s += v;
  }
  tsum[tid] = s;
  __syncthreads();
  for (int off = 1; off < 256; off <<= 1){
    int v = (tid >= off) ? tsum[tid-off] : 0;
    __syncthreads();
    tsum[tid] += v;
    __syncthreads();
  }
  int pre = (tid > 0) ? tsum[tid-1] : 0;
  #pragma unroll
  for (int j = 0; j < 13; ++j){
    int idx = tid*13 + j;
    if (idx < NWIN) offs[idx] = pre + loc[j];
  }
}

__global__ void scatter_kernel(const int* __restrict__ slot, const int* __restrict__ offs,
                               int* __restrict__ sorted){
  int w = blockIdx.x*256 + threadIdx.x;
  if (w >= NWIN) return;
  int o = offs[w];
  for (int s = 0; s < 144; ++s){
    int v = slot[w*144+s];
    if (v >= 0) sorted[o++] = v;
  }
}

__global__ void dense_kernel(const int* __restrict__ coords, int* __restrict__ dense){
  int i = blockIdx.x*256 + threadIdx.x;
  if (i >= N_PTS) return;
  dense[(coords[3*i]*SY + coords[3*i+1])*SX + coords[3*i+2]] = i;
}

__global__ __launch_bounds__(256) void bnstats_kernel(const float* __restrict__ x, float* __restrict__ stats){
  __shared__ float sh[256], shq[256];
  int tid = threadIdx.x;
  int c = tid & 127;
  float s = 0.f, q = 0.f;
  for (int r = blockIdx.x*2 + (tid>>7); r < N_PTS; r += gridDim.x*2){
    float v = x[(size_t)r*128 + c];
    s += v; q += v*v;
  }
  sh[tid] = s; shq[tid] = q;
  __syncthreads();
  if (tid < 128){
    atomicAdd(&stats[tid],     sh[tid] + sh[tid+128]);
    atomicAdd(&stats[128+tid], shq[tid] + shq[tid+128]);
  }
}

__global__ void bnfinish_kernel(const float* __restrict__ stats, const float* __restrict__ g,
                                const float* __restrict__ b, float* __restrict__ sb){
  int c = threadIdx.x;
  if (c >= 128) return;
  float mean = stats[c] * (1.0f/N_PTS);
  float var  = stats[128+c] * (1.0f/N_PTS) - mean*mean;
  float s = g[c] * rsqrtf(var + 1e-3f);
  sb[c] = s;
  sb[128+c] = b[c] - mean*s;
}

// pack W (row-major KxN, fp32) into per-lane MFMA B-fragment order, bf16.
__global__ void packw_kernel(const float* __restrict__ W, const float* __restrict__ scale,
                             short* __restrict__ out, int K, int Nn){
  int t = blockIdx.x*256 + threadIdx.x;
  if (t >= K*Nn) return;
  int e = t & 7, l = (t>>3) & 63, jt = (t>>9) & 7;
  int rest = t >> 12;
  int KT = K >> 5;
  int kt = rest % KT, np = rest / KT;
  int k = kt*32 + ((l>>4)<<3) + e;
  int col = np*128 + jt*16 + (l&15);
  float v = W[(size_t)k*Nn + col];
  if (scale) v *= scale[k];
  out[t] = (short)f2bf(v);
}

__global__ void packbias_kernel(const float* __restrict__ W, const float* __restrict__ bvec,
                                const float* __restrict__ base, float* __restrict__ out, int K, int Nn){
  int o = blockIdx.x*256 + threadIdx.x;
  if (o >= Nn) return;
  float s = base ? base[o] : 0.f;
  for (int k = 0; k < K; ++k) s += bvec[k] * W[(size_t)k*Nn + o];
  out[o] = s;
}

// pack conv weights into MFMA B-fragments: frag[tap][jt][lane][e] = W[tap][ci=(l>>4)*8+e][co=jt*16+(l&15)]
__global__ void packconv_kernel(const float* __restrict__ wk, const float* __restrict__ wh,
                                const float* __restrict__ ww, short* __restrict__ out){
  int t = blockIdx.x*256 + threadIdx.x;
  if (t >= 35*2*64*8) return;
  int e = t & 7, l = (t>>3) & 63, jt = (t>>9) & 1, tap = t >> 10;
  int ci = ((l>>4)<<3) + e;
  int co = jt*16 + (l&15);
  float v;
  if (tap < 9)       v = wk[((size_t)(tap*32) + ci)*32 + co];
  else if (tap < 22) v = wh[((size_t)((tap-9)*32) + ci)*32 + co];
  else               v = ww[((size_t)((tap-22)*32) + ci)*32 + co];
  out[t] = (short)f2bf(v);
}

// BN1 apply: feats2 (fp32) -> srcn bf16 only (no fp32 copy kept)
__global__ __launch_bounds__(256) void srcn_kernel(const float* __restrict__ f2, const float* __restrict__ sb,
                            short* __restrict__ sbuf){
  size_t i = (size_t)blockIdx.x*256 + threadIdx.x;
  if (i >= (size_t)N_PTS*32) return;
  int c4 = ((int)(i & 31)) * 4;
  float4 v = ((const float4*)f2)[i];
  float4 o;
  o.x = v.x*sb[c4+0] + sb[128+c4+0];
  o.y = v.y*sb[c4+1] + sb[128+c4+1];
  o.z = v.z*sb[c4+2] + sb[128+c4+2];
  o.w = v.w*sb[c4+3] + sb[128+c4+3];
  uint2 h; h.x = fpack2(o.x, o.y); h.y = fpack2(o.z, o.w);
  ((uint2*)sbuf)[i] = h;
}

// ---------------- generic 128-row-tile MFMA GEMM ----------------
// AMODE 0: A rows gathered from fp32 via sorted[]   AMODE 1: A rows direct bf16 (stride K)
// EPI 0: store bf16 (stride dstStride, +bias)
// EPI 1: feats2[sorted[row]] = addf[sorted[row]] + acc + bias, fused BN-stats atomics
// EPI 2: relu then store bf16
// EPI 3: outf[row] = addf[row] + acc + bias (fp32, stride 128)
// EPI 4: store bf16 into head-blocked qkv layout [g][np*8+jt][128][16]
template<int K, int AMODE, int EPI>
__global__ __launch_bounds__(256) void gemm_kernel(
    const float* __restrict__ Afp, const short* __restrict__ Abf,
    const int* __restrict__ sorted, const short* __restrict__ Wp,
    const float* __restrict__ bias, const float* __restrict__ addf,
    float* __restrict__ outf, short* __restrict__ outb, float* __restrict__ stats,
    int dstStride)
{
  extern __shared__ char smem[];   // A tile: 128 x K bf16, XOR-swizzled
  const int m0 = blockIdx.x * 128;
  const int np = blockIdx.y;
  const int tid = threadIdx.x;
  if (AMODE == 0){
    const int CHK = K/4;
    for (int c = tid; c < 128*CHK; c += 256){
      int r = c / CHK, q = c % CHK;
      const float* arow = Afp + (size_t)sorted[m0+r]*K;
      float4 v = ((const float4*)arow)[q];
      int off = r*(K*2) + q*8; off ^= ((r&7)<<4);
      *reinterpret_cast<uint2*>(smem+off) = make_uint2(fpack2(v.x,v.y), fpack2(v.z,v.w));
    }
  } else {
    const int CHK = K/8;
    for (int c = tid; c < 128*CHK; c += 256){
      int r = c / CHK, q = c % CHK;
      uint4 v = ((const uint4*)(Abf + (size_t)(m0+r)*K))[q];
      int off = r*(K*2) + q*16; off ^= ((r&7)<<4);
      *reinterpret_cast<uint4*>(smem+off) = v;
    }
  }
  __syncthreads();
  const int w = tid >> 6, l = tid & 63, lg = l >> 4, l16 = l & 15;
  f32x4 zacc; zacc[0]=0.f; zacc[1]=0.f; zacc[2]=0.f; zacc[3]=0.f;
  f32x4 acc[2][8];
  #pragma unroll
  for (int mt=0; mt<2; ++mt)
    #pragma unroll
    for (int jt=0; jt<8; ++jt) acc[mt][jt] = zacc;
  const int KT = K/32;
  #pragma unroll
  for (int kt = 0; kt < KT; ++kt){
    const short* wk = Wp + ((size_t)(np*KT + kt))*4096;
    bf16x8 bfr[8];
    #pragma unroll
    for (int jt=0; jt<8; ++jt)
      bfr[jt] = *reinterpret_cast<const bf16x8*>(wk + jt*512 + l*8);
    #pragma unroll
    for (int mt=0; mt<2; ++mt){
      int row = w*32 + mt*16 + l16;
      int off = row*(K*2) + kt*64 + lg*16; off ^= ((row&7)<<4);
      bf16x8 af = *reinterpret_cast<const bf16x8*>(smem + off);
      #pragma unroll
      for (int jt=0; jt<8; ++jt)
        acc[mt][jt] = __builtin_amdgcn_mfma_f32_16x16x32_bf16(af, bfr[jt], acc[mt][jt], 0, 0, 0);
    }
  }
  float psum[8], psq[8];
  #pragma unroll
  for (int jt=0; jt<8; ++jt){ psum[jt]=0.f; psq[jt]=0.f; }
  #pragma unroll
  for (int mt=0; mt<2; ++mt){
    #pragma unroll
    for (int jt=0; jt<8; ++jt){
      int col = np*128 + jt*16 + l16;
      float bv = bias ? bias[col] : 0.f;
      #pragma unroll
      for (int e=0; e<4; ++e){
        int row = m0 + w*32 + mt*16 + lg*4 + e;
        float v = acc[mt][jt][e] + bv;
        if (EPI == 0){
          outb[(size_t)row*dstStride + col] = (short)f2bf(v);
        } else if (EPI == 1){
          int gi = sorted[row];
          float fv = addf[(size_t)gi*128 + col] + v;
          outf[(size_t)gi*128 + col] = fv;
          psum[jt] += fv; psq[jt] += fv*fv;
        } else if (EPI == 2){
          outb[(size_t)row*dstStride + col] = (short)f2bf(fmaxf(v, 0.f));
        } else if (EPI == 3){
          outf[(size_t)row*128 + col] = addf[(size_t)row*128 + col] + v;
        } else {
          int r = row - m0;
          int blk = (m0 >> 7)*24 + np*8 + jt;
          outb[(size_t)blk*2048 + r*16 + l16] = (short)f2bf(v);
        }
      }
    }
  }
  if (EPI == 1){
    __syncthreads();
    float* cs = (float*)smem;      // 128 sums + 128 sumsq
    cs[tid] = 0.f;
    __syncthreads();
    float* cq = cs + 128;
    #pragma unroll
    for (int jt=0; jt<8; ++jt){
      atomicAdd(&cs[jt*16 + l16], psum[jt]);
      atomicAdd(&cq[jt*16 + l16], psq[jt]);
    }
    __syncthreads();
    if (tid < 128){
      atomicAdd(&stats[tid],     cs[tid]);
      atomicAdd(&stats[128+tid], cq[tid]);
    }
  }
}

// ---------------- fused grouped attention (head-split, blocked qkv) ----------------
// Grid (768 groups, 4 head-pairs). Block handles heads {2hp, 2hp+1} of one group.
// qkv blocked: [g][24][128 tok][16 ch]; blocks 0-7 = Q heads, 8-15 = K, 16-23 = V.
// S^T = mfma16(K_frag, Q_frag) -> P^T lands in the PV A-fragment layout (no LDS/barriers).
// Only V (2 heads, 8 KB) staged transposed in LDS with XOR swizzle.
__global__ __launch_bounds__(256) void attn_kernel(const short* __restrict__ qkv, short* __restrict__ attout){
  __shared__ char VT[8192];      // VT[32 ch][128 tok] bf16, swizzled
  const int g = blockIdx.x;
  const int hp = blockIdx.y;
  const int tid = threadIdx.x;
  const short* gb = qkv + (size_t)g*24*2048;
  for (int c = tid; c < 512; c += 256){
    int hh = c >> 8, idx = c & 255, token = idx >> 1, q = idx & 1;
    uint4 v = *(const uint4*)(gb + (16 + 2*hp + hh)*2048 + token*16 + q*8);
    const unsigned short* hv = (const unsigned short*)&v;
    #pragma unroll
    for (int j = 0; j < 8; ++j){
      int ch = hh*16 + q*8 + j;
      int F = ((ch & 7) ^ ((ch >> 3) & 7)) << 4;
      *(unsigned short*)(VT + ch*256 + ((token*2) ^ F)) = hv[j];
    }
  }
  __syncthreads();
  const int w = tid>>6, l = tid&63, lg = l>>4, l16 = l&15;
  const float sc2 = 0.12751744f;   // (1/sqrt(128)) * log2(e)
  f32x4 z4; z4[0]=0.f; z4[1]=0.f; z4[2]=0.f; z4[3]=0.f;
  #pragma unroll
  for (int hh = 0; hh < 2; ++hh){
    const int h = 2*hp + hh;
    const short* Qb = gb + h*2048;
    const short* Kb = gb + (8 + h)*2048;
    bf16x4 qf0 = *(const bf16x4*)(Qb + (w*32      + l16)*16 + lg*4);
    bf16x4 qf1 = *(const bf16x4*)(Qb + (w*32 + 16 + l16)*16 + lg*4);
    f32x4 s[8][2];
    #pragma unroll
    for (int kb=0; kb<8; ++kb){ s[kb][0] = z4; s[kb][1] = z4; }
    #pragma unroll
    for (int kb=0; kb<8; ++kb){
      bf16x4 kf = *(const bf16x4*)(Kb + (kb*16 + l16)*16 + lg*4);
      s[kb][0] = mfma16(kf, qf0, s[kb][0]);
      s[kb][1] = mfma16(kf, qf1, s[kb][1]);
    }
    // softmax over keys: lane holds P^T[key=kb*16+lg*4+e][q=l16] -> reduce across lg groups
    float inv0, inv1;
    #pragma unroll
    for (int mt=0; mt<2; ++mt){
      float m = -1e30f;
      #pragma unroll
      for (int kb=0; kb<8; ++kb)
        #pragma unroll
        for (int e=0; e<4; ++e) m = fmaxf(m, s[kb][mt][e]);
      m = fmaxf(m, __shfl_xor(m, 16));
      m = fmaxf(m, __shfl_xor(m, 32));
      float d = 0.f;
      #pragma unroll
      for (int kb=0; kb<8; ++kb)
        #pragma unroll
        for (int e=0; e<4; ++e){
          float p = exp2f((s[kb][mt][e] - m) * sc2);
          s[kb][mt][e] = p; d += p;
        }
      d += __shfl_xor(d, 16);
      d += __shfl_xor(d, 32);
      if (mt == 0) inv0 = 1.0f/d; else inv1 = 1.0f/d;
    }
    // PV: pa is register-local repack; vb from swizzled VT
    f32x4 o0 = z4, o1 = z4;
    const int cc = hh*16 + l16;
    const int F = ((cc & 7) ^ ((cc >> 3) & 7)) << 4;
    #pragma unroll
    for (int kb=0; kb<8; ++kb){
      bf16x4 vb = *(const bf16x4*)(VT + cc*256 + ((kb*32 + lg*8) ^ F));
      bf16x4 pa0, pa1;
      #pragma unroll
      for (int e=0; e<4; ++e){
        pa0[e] = (short)f2bf(s[kb][0][e] * inv0);
        pa1[e] = (short)f2bf(s[kb][1][e] * inv1);
      }
      o0 = mfma16(pa0, vb, o0);
      o1 = mfma16(pa1, vb, o1);
    }
    #pragma unroll
    for (int e=0; e<4; ++e){
      int row0 = g*128 + w*32      + lg*4 + e;
      int row1 = g*128 + w*32 + 16 + lg*4 + e;
      attout[(size_t)row0*128 + h*16 + l16] = (short)f2bf(o0[e]);
      attout[(size_t)row1*128 + h*16 + l16] = (short)f2bf(o1[e]);
    }
  }
}

// ---------------- submanifold convs via MFMA gather-GEMM ----------------
// template G: 0 = 3x3 on ch0:32 (tc=9), 1 = 1x13 on ch32:64, 2 = 13x1 on ch64:96 (tc=13)
template<int G>
__global__ __launch_bounds__(256) void conv_kernel(
    const short* __restrict__ wfrag, const short* __restrict__ srcnb,
    const int* __restrict__ dense, const int* __restrict__ coords,
    float* __restrict__ src)
{
  constexpr int TC   = (G==0) ? 9 : 13;
  constexpr int TAP0 = (G==0) ? 0 : ((G==1) ? 9 : 22);
  __shared__ int scoords[CPB*3];
  __shared__ int nid[CPB*16];
  extern __shared__ char nbf[];
  const int tid = threadIdx.x;
  const int p0 = blockIdx.x * CPB;
  if (tid < CPB*3) scoords[tid] = coords[p0*3 + tid];
  const int w = tid>>6, l = tid&63, lg = l>>4, l16 = l&15;
  const int mt = w & 1, jt = w >> 1;
  bf16x8 bw[TC];
  #pragma unroll
  for (int t = 0; t < TC; ++t)
    bw[t] = *reinterpret_cast<const bf16x8*>(wfrag + (((TAP0+t)*2 + jt)*64 + l)*8);
  __syncthreads();
  for (int i = tid; i < TC*CPB; i += 256){
    int tap = i >> 5, p = i & 31;
    int cb = scoords[p*3], cy = scoords[p*3+1], cx = scoords[p*3+2];
    int dy, dx;
    if (G==0){ dy = tap/3 - 1; dx = tap%3 - 1; }
    else if (G==1){ dy = 0; dx = tap - 6; }
    else { dy = tap - 6; dx = 0; }
    int ny = cy+dy, nx = cx+dx;
    int v = -1;
    if (ny>=0 && ny<SY && nx>=0 && nx<SX) v = dense[(cb*SY+ny)*SX + nx];
    nid[p*16 + tap] = v;
  }
  __syncthreads();
  for (int i = tid; i < TC*CPB*4; i += 256){
    int c = i & 3, s = i >> 2;
    int tap = s >> 5, p = s & 31;
    int v = nid[p*16 + tap];
    uint4 val = make_uint4(0,0,0,0);
    if (v >= 0) val = *(const uint4*)(srcnb + (size_t)v*128 + G*32 + c*8);
    int off = (tap*CPB + p)*80 + ((c*16) ^ ((p&3)<<4));
    *(uint4*)(nbf + off) = val;
  }
  __syncthreads();
  f32x4 acc; acc[0]=0.f; acc[1]=0.f; acc[2]=0.f; acc[3]=0.f;
  const int pA = mt*16 + l16;
  #pragma unroll
  for (int t = 0; t < TC; ++t){
    int off = (t*CPB + pA)*80 + ((lg*16) ^ ((pA&3)<<4));
    bf16x8 af = *reinterpret_cast<const bf16x8*>(nbf + off);
    acc = __builtin_amdgcn_mfma_f32_16x16x32_bf16(af, bw[t], acc, 0, 0, 0);
  }
  #pragma unroll
  for (int e = 0; e < 4; ++e){
    int pi = p0 + mt*16 + lg*4 + e;
    int c = G*32 + jt*16 + l16;
    unsigned short rv = ((const unsigned short*)srcnb)[(size_t)pi*128 + c];
    src[(size_t)pi*128 + c] = __uint_as_float((unsigned)rv << 16) + acc[e];
  }
}

// pass-through channels 96..127 (src = 2*srcn), bf16 copy of src, BN2 stats
__global__ __launch_bounds__(256) void post_kernel(float* __restrict__ src, const short* __restrict__ srcnb,
                           short* __restrict__ srcb, float* __restrict__ stats){
  __shared__ float ss[128], sq[128];
  int tid = threadIdx.x;
  if (tid < 128){ ss[tid]=0.f; sq[tid]=0.f; }
  __syncthreads();
  int c4 = (tid & 31) * 4;
  float a0=0,a1=0,a2=0,a3=0, q0=0,q1=0,q2=0,q3=0;
  for (int r = blockIdx.x*8 + (tid>>5); r < N_PTS; r += gridDim.x*8){
    size_t base = (size_t)r*128 + c4;
    float4 v;
    if (c4 < 96){
      v = *(const float4*)(src + base);
    } else {
      uint2 sn = *(const uint2*)(srcnb + base);
      float2 p0 = bfp2(sn.x), p1 = bfp2(sn.y);
      v = make_float4(2.f*p0.x, 2.f*p0.y, 2.f*p1.x, 2.f*p1.y);
      *(float4*)(src + base) = v;
    }
    uint2 h; h.x = fpack2(v.x, v.y); h.y = fpack2(v.z, v.w);
    *(uint2*)(srcb + base) = h;
    a0+=v.x; a1+=v.y; a2+=v.z; a3+=v.w;
    q0+=v.x*v.x; q1+=v.y*v.y; q2+=v.z*v.z; q3+=v.w*v.w;
  }
  atomicAdd(&ss[c4+0],a0); atomicAdd(&ss[c4+1],a1); atomicAdd(&ss[c4+2],a2); atomicAdd(&ss[c4+3],a3);
  atomicAdd(&sq[c4+0],q0); atomicAdd(&sq[c4+1],q1); atomicAdd(&sq[c4+2],q2); atomicAdd(&sq[c4+3],q3);
  __syncthreads();
  if (tid < 128){
    atomicAdd(&stats[tid],     ss[tid]);
    atomicAdd(&stats[128+tid], sq[tid]);
  }
}

// ---------------- launcher ----------------
extern "C" void kernel_launch(void* const* d_in, const int* in_sizes, int n_in,
                              void* d_out, int out_size, void* d_ws, size_t ws_size,
                              hipStream_t stream)
{
  const float* feats    = (const float*)d_in[0];
  const int*   coords   = (const int*)d_in[1];
  const float* qkv_w    = (const float*)d_in[2];
  const float* fc_out_w = (const float*)d_in[3];
  const float* fc_out_b = (const float*)d_in[4];
  const float* norm0_g  = (const float*)d_in[5];
  const float* norm0_b  = (const float*)d_in[6];
  const float* bn1_g    = (const float*)d_in[7];
  const float* bn1_b    = (const float*)d_in[8];
  const float* bn2_g    = (const float*)d_in[9];
  const float* bn2_b    = (const float*)d_in[10];
  const float* convk_w  = (const float*)d_in[11];
  const float* convh_w  = (const float*)d_in[12];
  const float* convw_w  = (const float*)d_in[13];
  const float* fc1_w    = (const float*)d_in[14];
  const float* fc1_b    = (const float*)d_in[15];
  const float* fc2_w    = (const float*)d_in[16];
  const float* fc2_b    = (const float*)d_in[17];
  float* out = (float*)d_out;
  char* ws = (char*)d_ws;

  int*   sorted = (int*)(ws + OFF_SORTED);
  int*   slot   = (int*)(ws + OFF_SLOT);
  int*   cnt    = (int*)(ws + OFF_CNT);
  int*   offs   = (int*)(ws + OFF_OFFS);
  float* stats0 = (float*)(ws + OFF_STATS);
  float* stats1 = stats0 + 256;
  float* stats2 = stats0 + 512;
  float* sb0    = (float*)(ws + OFF_SB);
  float* sb1    = sb0 + 256;
  float* sb2    = sb0 + 512;
  float* bqkv   = (float*)(ws + OFF_BQKV);
  float* b1     = (float*)(ws + OFF_B1);
  short* wqkv   = (short*)(ws + OFF_WQKV);
  short* wout   = (short*)(ws + OFF_WOUT);
  short* w1     = (short*)(ws + OFF_W1);
  short* w2     = (short*)(ws + OFF_W2);
  short* wconv  = (short*)(ws + OFF_WCONV);
  int*   dense  = (int*)(ws + OFF_DENSE);
  short* qkvb   = (short*)(ws + OFF_QKV);
  float* srcf   = (float*)(ws + OFF_SRC);
  short* srcb   = (short*)(ws + OFF_SRCB);
  short* att    = (short*)(ws + OFF_ATT);
  short* srcnb  = (short*)(ws + OFF_SRCNB);
  float* feats2 = (float*)(ws + OFF_F2);
  short* Hbuf   = (short*)(ws + OFF_H);

  // init (ws is poisoned 0xAA before every timed launch)
  fill_i32<<<(NSLOT+255)/256, 256, 0, stream>>>(slot, -1, NSLOT);
  fill_i32<<<(NDENSE+255)/256, 256, 0, stream>>>(dense, -1, NDENSE);
  fill_i32<<<3, 256, 0, stream>>>((int*)stats0, 0, 768);

  // window counting-sort (keys are unique)
  keys_kernel<<<(N_PTS+255)/256, 256, 0, stream>>>(coords, slot);
  wincount_kernel<<<(NWIN+255)/256, 256, 0, stream>>>(slot, cnt);
  scan_kernel<<<1, 256, 0, stream>>>(cnt, offs);
  scatter_kernel<<<(NWIN+255)/256, 256, 0, stream>>>(slot, offs, sorted);
  dense_kernel<<<(N_PTS+255)/256, 256, 0, stream>>>(coords, dense);

  // BN0 folded into qkv weights
  bnstats_kernel<<<512, 256, 0, stream>>>(feats, stats0);
  bnfinish_kernel<<<1, 128, 0, stream>>>(stats0, norm0_g, norm0_b, sb0);
  packw_kernel<<<(128*384+255)/256, 256, 0, stream>>>(qkv_w, sb0, wqkv, 128, 384);
  packbias_kernel<<<2, 256, 0, stream>>>(qkv_w, sb0+128, nullptr, bqkv, 128, 384);
  packw_kernel<<<(128*128+255)/256, 256, 0, stream>>>(fc_out_w, nullptr, wout, 128, 128);

  // qkv gemm (gathered rows, blocked output) -> head-split attention -> fc_out (+residual scatter, fused BN1 stats)
  gemm_kernel<128,0,4><<<dim3(768,3), 256, 32768, stream>>>(feats, nullptr, sorted, wqkv, bqkv, nullptr, nullptr, qkvb, nullptr, 0);
  attn_kernel<<<dim3(768,4), 256, 0, stream>>>(qkvb, att);
  gemm_kernel<128,1,1><<<dim3(768,1), 256, 32768, stream>>>(nullptr, att, sorted, wout, fc_out_b, feats, feats2, nullptr, stats1, 128);

  // BN1 scale/bias -> srcn bf16
  bnfinish_kernel<<<1, 128, 0, stream>>>(stats1, bn1_g, bn1_b, sb1);
  srcn_kernel<<<(N_PTS*32+255)/256, 256, 0, stream>>>(feats2, sb1, srcnb);

  // convs -> src (MFMA gather-GEMM), then BN2 stats
  packconv_kernel<<<(35*2*64*8+255)/256, 256, 0, stream>>>(convk_w, convh_w, convw_w, wconv);
  conv_kernel<0><<<N_PTS/CPB, 256,  9*CPB*80, stream>>>(wconv, srcnb, dense, coords, srcf);
  conv_kernel<1><<<N_PTS/CPB, 256, 13*CPB*80, stream>>>(wconv, srcnb, dense, coords, srcf);
  conv_kernel<2><<<N_PTS/CPB, 256, 13*CPB*80, stream>>>(wconv, srcnb, dense, coords, srcf);
  post_kernel<<<512, 256, 0, stream>>>(srcf, srcnb, srcb, stats2);
  bnfinish_kernel<<<1, 128, 0, stream>>>(stats2, bn2_g, bn2_b, sb2);

  // MLP with BN2 folded into fc1
  packw_kernel<<<(128*256+255)/256, 256, 0, stream>>>(fc1_w, sb2, w1, 128, 256);
  packbias_kernel<<<1, 256, 0, stream>>>(fc1_w, sb2+128, fc1_b, b1, 128, 256);
  packw_kernel<<<(256*128+255)/256, 256, 0, stream>>>(fc2_w, nullptr, w2, 256, 128);

  gemm_kernel<128,1,2><<<dim3(768,2), 256, 32768, stream>>>(nullptr, srcb, nullptr, w1, b1, nullptr, nullptr, Hbuf, nullptr, 256);
  gemm_kernel<256,1,3><<<dim3(768,1), 256, 65536, stream>>>(nullptr, Hbuf, nullptr, w2, fc2_b, srcf, out, nullptr, nullptr, 128);

  (void)in_sizes; (void)n_in; (void)out_size; (void)ws_size;
}

// Round 7
// 572.752 us; speedup vs baseline: 1.7066x; 1.0682x over previous
//
#include <hip/hip_runtime.h>

// ---------------- problem constants ----------------
#define N_PTS 98304
#define SY 468
#define SX 468
#define WIN 12
#define MWY 40
#define PER 1600          // mwx*mwy = 40*40
#define NWIN 3200         // B*PER
#define NSLOT (NWIN*144)
#define NDENSE (2*SY*SX)
#define CPB 32            // conv points per block

using bf16x8 = __attribute__((ext_vector_type(8))) short;
using bf16x4 = __attribute__((ext_vector_type(4))) short;
using f32x4  = __attribute__((ext_vector_type(4))) float;

__device__ __forceinline__ unsigned short f2bf(float f){
  unsigned u = __float_as_uint(f);
  u += 0x7fffu + ((u>>16)&1u);          // RNE
  return (unsigned short)(u>>16);
}
__device__ __forceinline__ float2 bfp2(unsigned u){
  float2 r; r.x = __uint_as_float(u<<16); r.y = __uint_as_float(u & 0xffff0000u); return r;
}
__device__ __forceinline__ unsigned fpack2(float a, float b){
  return (unsigned)f2bf(a) | ((unsigned)f2bf(b)<<16);
}

// K=16 bf16 MFMA (16x16x16): A/B = 4 bf16 (2 VGPR), C/D = 4 f32.
__device__ __forceinline__ f32x4 mfma16(bf16x4 a, bf16x4 b, f32x4 c){
#if __has_builtin(__builtin_amdgcn_mfma_f32_16x16x16bf16_1k)
  return __builtin_amdgcn_mfma_f32_16x16x16bf16_1k(a, b, c, 0, 0, 0);
#else
  asm volatile("v_mfma_f32_16x16x16_bf16 %0, %1, %2, %0\n\ts_nop 7\n\ts_nop 7"
               : "+v"(c) : "v"(a), "v"(b));
  return c;
#endif
}

// ---------------- workspace layout (bytes) ----------------
constexpr size_t OFF_SORTED = 0;
constexpr size_t OFF_SLOT   = OFF_SORTED + (size_t)N_PTS*4;
constexpr size_t OFF_CNT    = OFF_SLOT + (size_t)NSLOT*4;
constexpr size_t OFF_OFFS   = OFF_CNT + (size_t)NWIN*4;
constexpr size_t OFF_STATS  = OFF_OFFS + (size_t)NWIN*4;     // 3 x (sum[128],sumsq[128])
constexpr size_t OFF_SB     = OFF_STATS + 3*256*4;           // 3 x (scale[128],bias[128])
constexpr size_t OFF_BQKV   = OFF_SB + 3*256*4;              // float[384] (padded)
constexpr size_t OFF_B1     = OFF_BQKV + 512*4;              // float[256]
constexpr size_t OFF_WQKV   = OFF_B1 + 256*4;                // bf16 128x384 packed
constexpr size_t OFF_WOUT   = OFF_WQKV + (size_t)128*384*2;
constexpr size_t OFF_W1     = OFF_WOUT + (size_t)128*128*2;
constexpr size_t OFF_W2     = OFF_W1 + (size_t)128*256*2;
constexpr size_t OFF_WCONV  = OFF_W2 + (size_t)256*128*2;    // bf16 MFMA fragments [35][2][64][8]
constexpr size_t OFF_DENSE  = OFF_WCONV + (size_t)35*1024*2;
constexpr size_t OFF_CORS   = OFF_DENSE + (size_t)NDENSE*4;  // coords in sorted order, N x 3 int
constexpr size_t OFF_FB     = (OFF_CORS + (size_t)N_PTS*12 + 255) & ~(size_t)255; // featsb bf16 Nx128 (sorted)
constexpr size_t OFF_QKV    = (OFF_FB + (size_t)N_PTS*128*2 + 255) & ~(size_t)255; // qkv bf16 blocked [768][24][128][16]
constexpr size_t OFF_SRC    = OFF_QKV;                        // (reuse) src fp32 Nx128 (sorted)
constexpr size_t OFF_SRCB   = OFF_QKV + (size_t)N_PTS*128*4;  // (reuse) src bf16 Nx128 (sorted)
constexpr size_t OFF_ATT    = OFF_QKV + (size_t)N_PTS*384*2;  // attout bf16 Nx128 (sorted)
constexpr size_t OFF_SRCNB  = OFF_ATT;                        // (reuse) srcn bf16 (sorted)
constexpr size_t OFF_F2     = OFF_ATT + (size_t)N_PTS*128*2;  // feats2 bf16 Nx128 (sorted)
constexpr size_t OFF_H      = OFF_F2;                         // (reuse) H bf16 Nx256 (sorted)
// total ~182 MB

// ---------------- small utility kernels ----------------
__global__ void fill_i32(int* p, int v, int n){
  int i = blockIdx.x*256 + threadIdx.x;
  if (i < n) p[i] = v;
}

__global__ void keys_kernel(const int* __restrict__ coords, int* __restrict__ slot){
  int i = blockIdx.x*256 + threadIdx.x;
  if (i >= N_PTS) return;
  int cb = coords[3*i], cy = coords[3*i+1], cx = coords[3*i+2];
  int w = cb*PER + (cx/WIN)*MWY + (cy/WIN);
  int sub = (cx%WIN)*WIN + (cy%WIN);
  slot[w*144 + sub] = i;         // keys unique -> no collision
}

__global__ void wincount_kernel(const int* __restrict__ slot, int* __restrict__ cnt){
  int w = blockIdx.x*256 + threadIdx.x;
  if (w >= NWIN) return;
  int c = 0;
  for (int s = 0; s < 144; ++s) c += (slot[w*144+s] >= 0);
  cnt[w] = c;
}

__global__ void scan_kernel(const int* __restrict__ cnt, int* __restrict__ offs){
  __shared__ int tsum[256];
  int tid = threadIdx.x;
  int loc[13]; int s = 0;
  #pragma unroll
  for (int j = 0; j < 13; ++j){
    int idx = tid*13 + j;
    int v = (idx < NWIN) ? cnt[idx] : 0;
    loc[j] = s; s += v;
  }
  tsum[tid] = s;
  __syncthreads();
  for (int off = 1; off < 256; off <<= 1){
    int v = (tid >= off) ? tsum[tid-off] : 0;
    __syncthreads();
    tsum[tid] += v;
    __syncthreads();
  }
  int pre = (tid > 0) ? tsum[tid-1] : 0;
  #pragma unroll
  for (int j = 0; j < 13; ++j){
    int idx = tid*13 + j;
    if (idx < NWIN) offs[idx] = pre + loc[j];
  }
}

__global__ void scatter_kernel(const int* __restrict__ slot, const int* __restrict__ offs,
                               int* __restrict__ sorted){
  int w = blockIdx.x*256 + threadIdx.x;
  if (w >= NWIN) return;
  int o = offs[w];
  for (int s = 0; s < 144; ++s){
    int v = slot[w*144+s];
    if (v >= 0) sorted[o++] = v;
  }
}

// featsb[i] = bf16(feats[sorted[i]]); coordsS[i] = coords[sorted[i]]
__global__ __launch_bounds__(256) void gather_kernel(const float* __restrict__ feats,
    const int* __restrict__ coords, const int* __restrict__ sorted,
    short* __restrict__ featsb, int* __restrict__ coordsS){
  int t = blockIdx.x*256 + threadIdx.x;
  if (t >= N_PTS*32) return;
  int row = t >> 5, q = t & 31;
  int src = sorted[row];
  float4 v = ((const float4*)(feats + (size_t)src*128))[q];
  uint2 h; h.x = fpack2(v.x, v.y); h.y = fpack2(v.z, v.w);
  ((uint2*)featsb)[t] = h;
  if (q == 0){
    coordsS[3*row+0] = coords[3*src+0];
    coordsS[3*row+1] = coords[3*src+1];
    coordsS[3*row+2] = coords[3*src+2];
  }
}

// dense[coordS] = sorted position
__global__ void dense_kernel(const int* __restrict__ coordsS, int* __restrict__ dense){
  int i = blockIdx.x*256 + threadIdx.x;
  if (i >= N_PTS) return;
  dense[(coordsS[3*i]*SY + coordsS[3*i+1])*SX + coordsS[3*i+2]] = i;
}

// BN stats over bf16 [N][128]
__global__ __launch_bounds__(256) void bnstatsb_kernel(const short* __restrict__ x, float* __restrict__ stats){
  __shared__ float ss[128], sq[128];
  int tid = threadIdx.x;
  if (tid < 128){ ss[tid]=0.f; sq[tid]=0.f; }
  __syncthreads();
  int c8 = (tid & 15) * 8;
  float a[8], q[8];
  #pragma unroll
  for (int j=0;j<8;++j){ a[j]=0.f; q[j]=0.f; }
  for (int r = blockIdx.x*16 + (tid>>4); r < N_PTS; r += gridDim.x*16){
    uint4 v = *(const uint4*)(x + (size_t)r*128 + c8);
    const unsigned* wv = (const unsigned*)&v;
    #pragma unroll
    for (int k=0;k<4;++k){
      float2 p = bfp2(wv[k]);
      a[2*k]   += p.x; q[2*k]   += p.x*p.x;
      a[2*k+1] += p.y; q[2*k+1] += p.y*p.y;
    }
  }
  #pragma unroll
  for (int j=0;j<8;++j){
    atomicAdd(&ss[c8+j], a[j]);
    atomicAdd(&sq[c8+j], q[j]);
  }
  __syncthreads();
  if (tid < 128){
    atomicAdd(&stats[tid],     ss[tid]);
    atomicAdd(&stats[128+tid], sq[tid]);
  }
}

__global__ void bnfinish_kernel(const float* __restrict__ stats, const float* __restrict__ g,
                                const float* __restrict__ b, float* __restrict__ sb){
  int c = threadIdx.x;
  if (c >= 128) return;
  float mean = stats[c] * (1.0f/N_PTS);
  float var  = stats[128+c] * (1.0f/N_PTS) - mean*mean;
  float s = g[c] * rsqrtf(var + 1e-3f);
  sb[c] = s;
  sb[128+c] = b[c] - mean*s;
}

// pack W (row-major KxN, fp32) into per-lane MFMA B-fragment order, bf16.
__global__ void packw_kernel(const float* __restrict__ W, const float* __restrict__ scale,
                             short* __restrict__ out, int K, int Nn){
  int t = blockIdx.x*256 + threadIdx.x;
  if (t >= K*Nn) return;
  int e = t & 7, l = (t>>3) & 63, jt = (t>>9) & 7;
  int rest = t >> 12;
  int KT = K >> 5;
  int kt = rest % KT, np = rest / KT;
  int k = kt*32 + ((l>>4)<<3) + e;
  int col = np*128 + jt*16 + (l&15);
  float v = W[(size_t)k*Nn + col];
  if (scale) v *= scale[k];
  out[t] = (short)f2bf(v);
}

__global__ void packbias_kernel(const float* __restrict__ W, const float* __restrict__ bvec,
                                const float* __restrict__ base, float* __restrict__ out, int K, int Nn){
  int o = blockIdx.x*256 + threadIdx.x;
  if (o >= Nn) return;
  float s = base ? base[o] : 0.f;
  for (int k = 0; k < K; ++k) s += bvec[k] * W[(size_t)k*Nn + o];
  out[o] = s;
}

// pack conv weights into MFMA B-fragments: frag[tap][jt][lane][e] = W[tap][ci=(l>>4)*8+e][co=jt*16+(l&15)]
__global__ void packconv_kernel(const float* __restrict__ wk, const float* __restrict__ wh,
                                const float* __restrict__ ww, short* __restrict__ out){
  int t = blockIdx.x*256 + threadIdx.x;
  if (t >= 35*2*64*8) return;
  int e = t & 7, l = (t>>3) & 63, jt = (t>>9) & 1, tap = t >> 10;
  int ci = ((l>>4)<<3) + e;
  int co = jt*16 + (l&15);
  float v;
  if (tap < 9)       v = wk[((size_t)(tap*32) + ci)*32 + co];
  else if (tap < 22) v = wh[((size_t)((tap-9)*32) + ci)*32 + co];
  else               v = ww[((size_t)((tap-22)*32) + ci)*32 + co];
  out[t] = (short)f2bf(v);
}

// BN1 apply: feats2 bf16 -> srcn bf16
__global__ __launch_bounds__(256) void srcnb_kernel(const short* __restrict__ f2, const float* __restrict__ sb,
                            short* __restrict__ sbuf){
  int i = blockIdx.x*256 + threadIdx.x;
  if (i >= N_PTS*32) return;
  int c4 = (i & 31) * 4;
  uint2 v = ((const uint2*)f2)[i];
  float2 p0 = bfp2(v.x), p1 = bfp2(v.y);
  float o0 = p0.x*sb[c4+0] + sb[128+c4+0];
  float o1 = p0.y*sb[c4+1] + sb[128+c4+1];
  float o2 = p1.x*sb[c4+2] + sb[128+c4+2];
  float o3 = p1.y*sb[c4+3] + sb[128+c4+3];
  uint2 h; h.x = fpack2(o0, o1); h.y = fpack2(o2, o3);
  ((uint2*)sbuf)[i] = h;
}

// ---------------- qkv GEMM: A staged once, np looped, blocked epilogue ----------------
__global__ __launch_bounds__(256) void qkvgemm_kernel(const short* __restrict__ Abf,
    const short* __restrict__ Wp, const float* __restrict__ bias, short* __restrict__ outb){
  __shared__ char smem[32768];
  const int m0 = blockIdx.x * 128;
  const int tid = threadIdx.x;
  for (int c = tid; c < 128*16; c += 256){
    int r = c >> 4, q = c & 15;
    uint4 v = ((const uint4*)(Abf + (size_t)(m0+r)*128))[q];
    int off = r*256 + q*16; off ^= ((r&7)<<4);
    *reinterpret_cast<uint4*>(smem+off) = v;
  }
  __syncthreads();
  const int w = tid>>6, l = tid&63, lg = l>>4, l16 = l&15;
  f32x4 zacc; zacc[0]=0.f; zacc[1]=0.f; zacc[2]=0.f; zacc[3]=0.f;
  for (int np = 0; np < 3; ++np){
    f32x4 acc[2][8];
    #pragma unroll
    for (int mt=0; mt<2; ++mt)
      #pragma unroll
      for (int jt=0; jt<8; ++jt) acc[mt][jt] = zacc;
    #pragma unroll
    for (int kt = 0; kt < 4; ++kt){
      const short* wk = Wp + ((size_t)(np*4 + kt))*4096;
      bf16x8 bfr[8];
      #pragma unroll
      for (int jt=0; jt<8; ++jt)
        bfr[jt] = *reinterpret_cast<const bf16x8*>(wk + jt*512 + l*8);
      #pragma unroll
      for (int mt=0; mt<2; ++mt){
        int row = w*32 + mt*16 + l16;
        int off = row*256 + kt*64 + lg*16; off ^= ((row&7)<<4);
        bf16x8 af = *reinterpret_cast<const bf16x8*>(smem + off);
        #pragma unroll
        for (int jt=0; jt<8; ++jt)
          acc[mt][jt] = __builtin_amdgcn_mfma_f32_16x16x32_bf16(af, bfr[jt], acc[mt][jt], 0, 0, 0);
      }
    }
    #pragma unroll
    for (int mt=0; mt<2; ++mt){
      #pragma unroll
      for (int jt=0; jt<8; ++jt){
        float bv = bias[np*128 + jt*16 + l16];
        int blk = blockIdx.x*24 + np*8 + jt;
        #pragma unroll
        for (int e=0; e<4; ++e){
          int r = w*32 + mt*16 + lg*4 + e;
          outb[(size_t)blk*2048 + r*16 + l16] = (short)f2bf(acc[mt][jt][e] + bv);
        }
      }
    }
  }
}

// ---------------- generic 128-row-tile MFMA GEMM (bf16 A, sorted-linear) ----------------
// EPI 1: fv = addb[row] + acc + bias; outb bf16 linear; fused BN-stats atomics
// EPI 2: relu then store bf16 (stride dstStride)
// EPI 5: out[sorted[row]] = addf[row] + acc + bias (fp32 scatter, final output)
template<int K, int EPI>
__global__ __launch_bounds__(256) void gemm_kernel(
    const short* __restrict__ Abf, const int* __restrict__ sorted,
    const short* __restrict__ Wp, const float* __restrict__ bias,
    const short* __restrict__ addb, const float* __restrict__ addf,
    float* __restrict__ outf, short* __restrict__ outb, float* __restrict__ stats,
    int dstStride)
{
  extern __shared__ char smem[];   // A tile: 128 x K bf16, XOR-swizzled
  const int m0 = blockIdx.x * 128;
  const int np = blockIdx.y;
  const int tid = threadIdx.x;
  const int CHK = K/8;
  for (int c = tid; c < 128*CHK; c += 256){
    int r = c / CHK, q = c % CHK;
    uint4 v = ((const uint4*)(Abf + (size_t)(m0+r)*K))[q];
    int off = r*(K*2) + q*16; off ^= ((r&7)<<4);
    *reinterpret_cast<uint4*>(smem+off) = v;
  }
  __syncthreads();
  const int w = tid >> 6, l = tid & 63, lg = l >> 4, l16 = l & 15;
  f32x4 zacc; zacc[0]=0.f; zacc[1]=0.f; zacc[2]=0.f; zacc[3]=0.f;
  f32x4 acc[2][8];
  #pragma unroll
  for (int mt=0; mt<2; ++mt)
    #pragma unroll
    for (int jt=0; jt<8; ++jt) acc[mt][jt] = zacc;
  const int KT = K/32;
  #pragma unroll
  for (int kt = 0; kt < KT; ++kt){
    const short* wk = Wp + ((size_t)(np*KT + kt))*4096;
    bf16x8 bfr[8];
    #pragma unroll
    for (int jt=0; jt<8; ++jt)
      bfr[jt] = *reinterpret_cast<const bf16x8*>(wk + jt*512 + l*8);
    #pragma unroll
    for (int mt=0; mt<2; ++mt){
      int row = w*32 + mt*16 + l16;
      int off = row*(K*2) + kt*64 + lg*16; off ^= ((row&7)<<4);
      bf16x8 af = *reinterpret_cast<const bf16x8*>(smem + off);
      #pragma unroll
      for (int jt=0; jt<8; ++jt)
        acc[mt][jt] = __builtin_amdgcn_mfma_f32_16x16x32_bf16(af, bfr[jt], acc[mt][jt], 0, 0, 0);
    }
  }
  float psum[8], psq[8];
  #pragma unroll
  for (int jt=0; jt<8; ++jt){ psum[jt]=0.f; psq[jt]=0.f; }
  #pragma unroll
  for (int mt=0; mt<2; ++mt){
    #pragma unroll
    for (int jt=0; jt<8; ++jt){
      int col = np*128 + jt*16 + l16;
      float bv = bias ? bias[col] : 0.f;
      #pragma unroll
      for (int e=0; e<4; ++e){
        int row = m0 + w*32 + mt*16 + lg*4 + e;
        float v = acc[mt][jt][e] + bv;
        if (EPI == 1){
          unsigned short rb = ((const unsigned short*)addb)[(size_t)row*128 + col];
          float fv = __uint_as_float((unsigned)rb << 16) + v;
          outb[(size_t)row*128 + col] = (short)f2bf(fv);
          psum[jt] += fv; psq[jt] += fv*fv;
        } else if (EPI == 2){
          outb[(size_t)row*dstStride + col] = (short)f2bf(fmaxf(v, 0.f));
        } else {
          outf[(size_t)sorted[row]*128 + col] = addf[(size_t)row*128 + col] + v;
        }
      }
    }
  }
  if (EPI == 1){
    __syncthreads();
    float* cs = (float*)smem;      // 128 sums + 128 sumsq
    cs[tid] = 0.f;
    __syncthreads();
    float* cq = cs + 128;
    #pragma unroll
    for (int jt=0; jt<8; ++jt){
      atomicAdd(&cs[jt*16 + l16], psum[jt]);
      atomicAdd(&cq[jt*16 + l16], psq[jt]);
    }
    __syncthreads();
    if (tid < 128){
      atomicAdd(&stats[tid],     cs[tid]);
      atomicAdd(&stats[128+tid], cq[tid]);
    }
  }
}

// ---------------- fused grouped attention (head-split, blocked qkv) ----------------
__global__ __launch_bounds__(256) void attn_kernel(const short* __restrict__ qkv, short* __restrict__ attout){
  __shared__ char VT[8192];      // VT[32 ch][128 tok] bf16, swizzled
  const int g = blockIdx.x;
  const int hp = blockIdx.y;
  const int tid = threadIdx.x;
  const short* gb = qkv + (size_t)g*24*2048;
  for (int c = tid; c < 512; c += 256){
    int hh = c >> 8, idx = c & 255, token = idx >> 1, q = idx & 1;
    uint4 v = *(const uint4*)(gb + (16 + 2*hp + hh)*2048 + token*16 + q*8);
    const unsigned short* hv = (const unsigned short*)&v;
    #pragma unroll
    for (int j = 0; j < 8; ++j){
      int ch = hh*16 + q*8 + j;
      int F = ((ch & 7) ^ ((ch >> 3) & 7)) << 4;
      *(unsigned short*)(VT + ch*256 + ((token*2) ^ F)) = hv[j];
    }
  }
  __syncthreads();
  const int w = tid>>6, l = tid&63, lg = l>>4, l16 = l&15;
  const float sc2 = 0.12751744f;   // (1/sqrt(128)) * log2(e)
  f32x4 z4; z4[0]=0.f; z4[1]=0.f; z4[2]=0.f; z4[3]=0.f;
  #pragma unroll
  for (int hh = 0; hh < 2; ++hh){
    const int h = 2*hp + hh;
    const short* Qb = gb + h*2048;
    const short* Kb = gb + (8 + h)*2048;
    bf16x4 qf0 = *(const bf16x4*)(Qb + (w*32      + l16)*16 + lg*4);
    bf16x4 qf1 = *(const bf16x4*)(Qb + (w*32 + 16 + l16)*16 + lg*4);
    f32x4 s[8][2];
    #pragma unroll
    for (int kb=0; kb<8; ++kb){ s[kb][0] = z4; s[kb][1] = z4; }
    #pragma unroll
    for (int kb=0; kb<8; ++kb){
      bf16x4 kf = *(const bf16x4*)(Kb + (kb*16 + l16)*16 + lg*4);
      s[kb][0] = mfma16(kf, qf0, s[kb][0]);
      s[kb][1] = mfma16(kf, qf1, s[kb][1]);
    }
    float inv0, inv1;
    #pragma unroll
    for (int mt=0; mt<2; ++mt){
      float m = -1e30f;
      #pragma unroll
      for (int kb=0; kb<8; ++kb)
        #pragma unroll
        for (int e=0; e<4; ++e) m = fmaxf(m, s[kb][mt][e]);
      m = fmaxf(m, __shfl_xor(m, 16));
      m = fmaxf(m, __shfl_xor(m, 32));
      float d = 0.f;
      #pragma unroll
      for (int kb=0; kb<8; ++kb)
        #pragma unroll
        for (int e=0; e<4; ++e){
          float p = exp2f((s[kb][mt][e] - m) * sc2);
          s[kb][mt][e] = p; d += p;
        }
      d += __shfl_xor(d, 16);
      d += __shfl_xor(d, 32);
      if (mt == 0) inv0 = 1.0f/d; else inv1 = 1.0f/d;
    }
    f32x4 o0 = z4, o1 = z4;
    const int cc = hh*16 + l16;
    const int F = ((cc & 7) ^ ((cc >> 3) & 7)) << 4;
    #pragma unroll
    for (int kb=0; kb<8; ++kb){
      bf16x4 vb = *(const bf16x4*)(VT + cc*256 + ((kb*32 + lg*8) ^ F));
      bf16x4 pa0, pa1;
      #pragma unroll
      for (int e=0; e<4; ++e){
        pa0[e] = (short)f2bf(s[kb][0][e] * inv0);
        pa1[e] = (short)f2bf(s[kb][1][e] * inv1);
      }
      o0 = mfma16(pa0, vb, o0);
      o1 = mfma16(pa1, vb, o1);
    }
    #pragma unroll
    for (int e=0; e<4; ++e){
      int row0 = g*128 + w*32      + lg*4 + e;
      int row1 = g*128 + w*32 + 16 + lg*4 + e;
      attout[(size_t)row0*128 + h*16 + l16] = (short)f2bf(o0[e]);
      attout[(size_t)row1*128 + h*16 + l16] = (short)f2bf(o1[e]);
    }
  }
}

// ---------------- submanifold convs via MFMA gather-GEMM (sorted order) ----------------
template<int G>
__global__ __launch_bounds__(256) void conv_kernel(
    const short* __restrict__ wfrag, const short* __restrict__ srcnb,
    const int* __restrict__ dense, const int* __restrict__ coordsS,
    float* __restrict__ src)
{
  constexpr int TC   = (G==0) ? 9 : 13;
  constexpr int TAP0 = (G==0) ? 0 : ((G==1) ? 9 : 22);
  __shared__ int scoords[CPB*3];
  __shared__ int nid[CPB*16];
  extern __shared__ char nbf[];
  const int tid = threadIdx.x;
  const int p0 = blockIdx.x * CPB;
  if (tid < CPB*3) scoords[tid] = coordsS[p0*3 + tid];
  const int w = tid>>6, l = tid&63, lg = l>>4, l16 = l&15;
  const int mt = w & 1, jt = w >> 1;
  bf16x8 bw[TC];
  #pragma unroll
  for (int t = 0; t < TC; ++t)
    bw[t] = *reinterpret_cast<const bf16x8*>(wfrag + (((TAP0+t)*2 + jt)*64 + l)*8);
  __syncthreads();
  for (int i = tid; i < TC*CPB; i += 256){
    int tap = i >> 5, p = i & 31;
    int cb = scoords[p*3], cy = scoords[p*3+1], cx = scoords[p*3+2];
    int dy, dx;
    if (G==0){ dy = tap/3 - 1; dx = tap%3 - 1; }
    else if (G==1){ dy = 0; dx = tap - 6; }
    else { dy = tap - 6; dx = 0; }
    int ny = cy+dy, nx = cx+dx;
    int v = -1;
    if (ny>=0 && ny<SY && nx>=0 && nx<SX) v = dense[(cb*SY+ny)*SX + nx];
    nid[p*16 + tap] = v;
  }
  __syncthreads();
  for (int i = tid; i < TC*CPB*4; i += 256){
    int c = i & 3, s = i >> 2;
    int tap = s >> 5, p = s & 31;
    int v = nid[p*16 + tap];
    uint4 val = make_uint4(0,0,0,0);
    if (v >= 0) val = *(const uint4*)(srcnb + (size_t)v*128 + G*32 + c*8);
    int off = (tap*CPB + p)*80 + ((c*16) ^ ((p&3)<<4));
    *(uint4*)(nbf + off) = val;
  }
  __syncthreads();
  f32x4 acc; acc[0]=0.f; acc[1]=0.f; acc[2]=0.f; acc[3]=0.f;
  const int pA = mt*16 + l16;
  #pragma unroll
  for (int t = 0; t < TC; ++t){
    int off = (t*CPB + pA)*80 + ((lg*16) ^ ((pA&3)<<4));
    bf16x8 af = *reinterpret_cast<const bf16x8*>(nbf + off);
    acc = __builtin_amdgcn_mfma_f32_16x16x32_bf16(af, bw[t], acc, 0, 0, 0);
  }
  #pragma unroll
  for (int e = 0; e < 4; ++e){
    int pi = p0 + mt*16 + lg*4 + e;
    int c = G*32 + jt*16 + l16;
    unsigned short rv = ((const unsigned short*)srcnb)[(size_t)pi*128 + c];
    src[(size_t)pi*128 + c] = __uint_as_float((unsigned)rv << 16) + acc[e];
  }
}

// pass-through channels 96..127 (src = 2*srcn), bf16 copy of src, BN2 stats
__global__ __launch_bounds__(256) void post_kernel(float* __restrict__ src, const short* __restrict__ srcnb,
                           short* __restrict__ srcb, float* __restrict__ stats){
  __shared__ float ss[128], sq[128];
  int tid = threadIdx.x;
  if (tid < 128){ ss[tid]=0.f; sq[tid]=0.f; }
  __syncthreads();
  int c4 = (tid & 31) * 4;
  float a0=0,a1=0,a2=0,a3=0, q0=0,q1=0,q2=0,q3=0;
  for (int r = blockIdx.x*8 + (tid>>5); r < N_PTS; r += gridDim.x*8){
    size_t base = (size_t)r*128 + c4;
    float4 v;
    if (c4 < 96){
      v = *(const float4*)(src + base);
    } else {
      uint2 sn = *(const uint2*)(srcnb + base);
      float2 p0 = bfp2(sn.x), p1 = bfp2(sn.y);
      v = make_float4(2.f*p0.x, 2.f*p0.y, 2.f*p1.x, 2.f*p1.y);
      *(float4*)(src + base) = v;
    }
    uint2 h; h.x = fpack2(v.x, v.y); h.y = fpack2(v.z, v.w);
    *(uint2*)(srcb + base) = h;
    a0+=v.x; a1+=v.y; a2+=v.z; a3+=v.w;
    q0+=v.x*v.x; q1+=v.y*v.y; q2+=v.z*v.z; q3+=v.w*v.w;
  }
  atomicAdd(&ss[c4+0],a0); atomicAdd(&ss[c4+1],a1); atomicAdd(&ss[c4+2],a2); atomicAdd(&ss[c4+3],a3);
  atomicAdd(&sq[c4+0],q0); atomicAdd(&sq[c4+1],q1); atomicAdd(&sq[c4+2],q2); atomicAdd(&sq[c4+3],q3);
  __syncthreads();
  if (tid < 128){
    atomicAdd(&stats[tid],     ss[tid]);
    atomicAdd(&stats[128+tid], sq[tid]);
  }
}

// ---------------- launcher ----------------
extern "C" void kernel_launch(void* const* d_in, const int* in_sizes, int n_in,
                              void* d_out, int out_size, void* d_ws, size_t ws_size,
                              hipStream_t stream)
{
  const float* feats    = (const float*)d_in[0];
  const int*   coords   = (const int*)d_in[1];
  const float* qkv_w    = (const float*)d_in[2];
  const float* fc_out_w = (const float*)d_in[3];
  const float* fc_out_b = (const float*)d_in[4];
  const float* norm0_g  = (const float*)d_in[5];
  const float* norm0_b  = (const float*)d_in[6];
  const float* bn1_g    = (const float*)d_in[7];
  const float* bn1_b    = (const float*)d_in[8];
  const float* bn2_g    = (const float*)d_in[9];
  const float* bn2_b    = (const float*)d_in[10];
  const float* convk_w  = (const float*)d_in[11];
  const float* convh_w  = (const float*)d_in[12];
  const float* convw_w  = (const float*)d_in[13];
  const float* fc1_w    = (const float*)d_in[14];
  const float* fc1_b    = (const float*)d_in[15];
  const float* fc2_w    = (const float*)d_in[16];
  const float* fc2_b    = (const float*)d_in[17];
  float* out = (float*)d_out;
  char* ws = (char*)d_ws;

  int*   sorted = (int*)(ws + OFF_SORTED);
  int*   slot   = (int*)(ws + OFF_SLOT);
  int*   cnt    = (int*)(ws + OFF_CNT);
  int*   offs   = (int*)(ws + OFF_OFFS);
  float* stats0 = (float*)(ws + OFF_STATS);
  float* stats1 = stats0 + 256;
  float* stats2 = stats0 + 512;
  float* sb0    = (float*)(ws + OFF_SB);
  float* sb1    = sb0 + 256;
  float* sb2    = sb0 + 512;
  float* bqkv   = (float*)(ws + OFF_BQKV);
  float* b1     = (float*)(ws + OFF_B1);
  short* wqkv   = (short*)(ws + OFF_WQKV);
  short* wout   = (short*)(ws + OFF_WOUT);
  short* w1     = (short*)(ws + OFF_W1);
  short* w2     = (short*)(ws + OFF_W2);
  short* wconv  = (short*)(ws + OFF_WCONV);
  int*   dense  = (int*)(ws + OFF_DENSE);
  int*   coordsS= (int*)(ws + OFF_CORS);
  short* featsb = (short*)(ws + OFF_FB);
  short* qkvb   = (short*)(ws + OFF_QKV);
  float* srcf   = (float*)(ws + OFF_SRC);
  short* srcb   = (short*)(ws + OFF_SRCB);
  short* att    = (short*)(ws + OFF_ATT);
  short* srcnb  = (short*)(ws + OFF_SRCNB);
  short* feats2 = (short*)(ws + OFF_F2);
  short* Hbuf   = (short*)(ws + OFF_H);

  // init (ws is poisoned 0xAA before every timed launch)
  fill_i32<<<(NSLOT+255)/256, 256, 0, stream>>>(slot, -1, NSLOT);
  fill_i32<<<(NDENSE+255)/256, 256, 0, stream>>>(dense, -1, NDENSE);
  fill_i32<<<3, 256, 0, stream>>>((int*)stats0, 0, 768);

  // window counting-sort (keys are unique) -> sorted-order gather
  keys_kernel<<<(N_PTS+255)/256, 256, 0, stream>>>(coords, slot);
  wincount_kernel<<<(NWIN+255)/256, 256, 0, stream>>>(slot, cnt);
  scan_kernel<<<1, 256, 0, stream>>>(cnt, offs);
  scatter_kernel<<<(NWIN+255)/256, 256, 0, stream>>>(slot, offs, sorted);
  gather_kernel<<<(N_PTS*32+255)/256, 256, 0, stream>>>(feats, coords, sorted, featsb, coordsS);
  dense_kernel<<<(N_PTS+255)/256, 256, 0, stream>>>(coordsS, dense);

  // BN0 folded into qkv weights (stats from bf16 sorted copy)
  bnstatsb_kernel<<<512, 256, 0, stream>>>(featsb, stats0);
  bnfinish_kernel<<<1, 128, 0, stream>>>(stats0, norm0_g, norm0_b, sb0);
  packw_kernel<<<(128*384+255)/256, 256, 0, stream>>>(qkv_w, sb0, wqkv, 128, 384);
  packbias_kernel<<<2, 256, 0, stream>>>(qkv_w, sb0+128, nullptr, bqkv, 128, 384);
  packw_kernel<<<(128*128+255)/256, 256, 0, stream>>>(fc_out_w, nullptr, wout, 128, 128);

  // qkv gemm (linear A, np-loop) -> head-split attention -> fc_out (linear, fused BN1 stats)
  qkvgemm_kernel<<<768, 256, 0, stream>>>(featsb, wqkv, bqkv, qkvb);
  attn_kernel<<<dim3(768,4), 256, 0, stream>>>(qkvb, att);
  gemm_kernel<128,1><<<dim3(768,1), 256, 32768, stream>>>(att, nullptr, wout, fc_out_b, featsb, nullptr, nullptr, feats2, stats1, 128);

  // BN1 scale/bias -> srcn bf16
  bnfinish_kernel<<<1, 128, 0, stream>>>(stats1, bn1_g, bn1_b, sb1);
  srcnb_kernel<<<(N_PTS*32+255)/256, 256, 0, stream>>>(feats2, sb1, srcnb);

  // convs -> src (MFMA gather-GEMM), then BN2 stats
  packconv_kernel<<<(35*2*64*8+255)/256, 256, 0, stream>>>(convk_w, convh_w, convw_w, wconv);
  conv_kernel<0><<<N_PTS/CPB, 256,  9*CPB*80, stream>>>(wconv, srcnb, dense, coordsS, srcf);
  conv_kernel<1><<<N_PTS/CPB, 256, 13*CPB*80, stream>>>(wconv, srcnb, dense, coordsS, srcf);
  conv_kernel<2><<<N_PTS/CPB, 256, 13*CPB*80, stream>>>(wconv, srcnb, dense, coordsS, srcf);
  post_kernel<<<512, 256, 0, stream>>>(srcf, srcnb, srcb, stats2);
  bnfinish_kernel<<<1, 128, 0, stream>>>(stats2, bn2_g, bn2_b, sb2);

  // MLP with BN2 folded into fc1; final fp32 scatter to original order
  packw_kernel<<<(128*256+255)/256, 256, 0, stream>>>(fc1_w, sb2, w1, 128, 256);
  packbias_kernel<<<1, 256, 0, stream>>>(fc1_w, sb2+128, fc1_b, b1, 128, 256);
  packw_kernel<<<(256*128+255)/256, 256, 0, stream>>>(fc2_w, nullptr, w2, 256, 128);

  gemm_kernel<128,2><<<dim3(768,2), 256, 32768, stream>>>(srcb, nullptr, w1, b1, nullptr, nullptr, nullptr, Hbuf, nullptr, 256);
  gemm_kernel<256,5><<<dim3(768,1), 256, 65536, stream>>>(Hbuf, sorted, w2, fc2_b, nullptr, srcf, out, nullptr, nullptr, 128);

  (void)in_sizes; (void)n_in; (void)out_size; (void)ws_size;
}